// Round 5
// baseline (386.530 us; speedup 1.0000x reference)
//
#include <hip/hip_runtime.h>
#include <hip/hip_bf16.h>
#include <cmath>

// ============================================================================
// DeepTemplateMatchingModule on MI355X — round 18.
// R13/R16/R17 invariant: 99us at occupancy 47/26/17%, atomics 5x apart,
// ILP 4x apart -> not occupancy-, traffic-, or chain-bound. Invariant across
// all three: ~27-30K barrier-crossings and the conv->s_out->pool->poolT->lin
// serialized phase chain. MfmaUtil 19.6% back-computes to ~32cyc/MFMA:
// pipes idle at barriers. R18: phase-structure attack — wave tile (chalf,
// thalf) computes BOTH pool parities in-register; pairmax in-reg (bit-exact:
// f2bf monotone) kills s_out (32 scalar writes + 6 reads -> 16 writes +
// 3 reads into pairmaxed s_m01); both hh merged between one barrier pair:
// conv 52 MFMA (4 indep 13-chains) -> BAR -> pool(2h) -> BAR -> lin 8 MFMA.
// Barriers/by 5->3 (27K->18.7K crossings). LDS 40KB. bb[2][4] prefetched.
// ============================================================================

typedef unsigned short u16;
typedef unsigned int u32;
typedef __attribute__((ext_vector_type(8))) short bf16x8;
typedef __attribute__((ext_vector_type(8))) unsigned short u16x8;
typedef __attribute__((ext_vector_type(16))) float f32x16;

__device__ __forceinline__ u16 f2bf(float f) {
  unsigned int x = __float_as_uint(f);
  return (u16)((x + 0x7fffu + ((x >> 16) & 1u)) >> 16);
}
__device__ __forceinline__ float bf2f(u16 v) {
  return __uint_as_float(((unsigned int)v) << 16);
}
__device__ __forceinline__ u32 f2bf_pk(float a, float b) {
  __hip_bfloat162 h = __float22bfloat162_rn(float2{a, b});
  u32 r;
  __builtin_memcpy(&r, &h, 4);  // low 16 = a, high 16 = b
  return r;
}

// ---- workspace layout (float offsets) ----
static const size_t OFF_BEFF_E  = 0;          // 64
static const size_t OFF_BEFF_T  = 64;
static const size_t OFF_BIAS2_E = 128;        // 192
static const size_t OFF_BIAS2_T = 320;
static const size_t OFF_WKX_E   = 512;        // 4 parities x 13x64x16 u16 = 26624 f
static const size_t OFF_WKX_T   = 27136;      // 26624 f
static const size_t OFF_W12P_E  = 53760;      // 9248
static const size_t OFF_W12P_T  = 63008;      // 9248
static const size_t OFF_B12_E   = 72256;      // 32
static const size_t OFF_B12_T   = 72288;      // 32
static const size_t OFF_LWT1_E  = 72320;      // lwT1[h][n][c] bf16: 237568 u16 = 118784 f
static const size_t OFF_LWT1_T  = 191104;     // 118784 f
static const size_t OFF_ATT     = 309888;     // 8128 f (raw logits)
static const size_t OFF_XYBF_E  = 318016;     // 260096 f (4x2032x64 u16)
static const size_t OFF_XYBF_T  = 578112;     // 131072 f (4x1024x64 u16)
static const size_t OFF_TTBF    = 709184;     // 131072 f (t^T: 4x64x1024 u16)
// contiguous zero region (zeroed by prep): lin_e, lin_t, PV, red, rowsum
static const size_t OFF_LIN_E   = 840256;     // 520192 f
static const size_t OFF_LIN_T   = 1360448;    // 262144 f
static const size_t OFF_PV      = 1622592;    // 520192 f
static const size_t OFF_RED     = 2142784;    // 256 f
static const size_t OFF_RSUM    = 2143040;    // 4096 f
static const size_t ZERO_F4     = 326720;     // 1,306,880 f / 4
static const size_t ZSTRIDE     = 617;        // 530 * 617 >= 326720
static const size_t OFF_GI_E    = 2147136;    // 1,560,576 f
static const size_t OFF_GI_T    = 3707712;    // 786,432 f
static const size_t OFF_P       = 4494144;    // u16: 8,323,072 u16 (4,161,536 f)

// ---------------------------------------------------------------------------
// prep: zero region + compose12 (bx<64) + gi_bias (64..65) + lw->lwT1 (>=66).
// lwT1[h][n][c] = bf16(lw[n][c*58+h]); 237,568 els per branch.
// ---------------------------------------------------------------------------
__global__ __launch_bounds__(320) void prep_kernel(
    const float* __restrict__ w1e, const float* __restrict__ b1e,
    const float* __restrict__ w2e, const float* __restrict__ b2e,
    const float* __restrict__ w1t, const float* __restrict__ b1t,
    const float* __restrict__ w2t, const float* __restrict__ b2t,
    float* __restrict__ w12p_e, float* __restrict__ w12p_t,
    float* __restrict__ b12o_e, float* __restrict__ b12o_t,
    const float* __restrict__ wih_e, const float* __restrict__ bih_e,
    const float* __restrict__ lb_e, float* __restrict__ bias2_e,
    const float* __restrict__ wih_t, const float* __restrict__ bih_t,
    const float* __restrict__ lb_t, float* __restrict__ bias2_t,
    const float* __restrict__ lwe, const float* __restrict__ lwt,
    u16* __restrict__ lwt1_e, u16* __restrict__ lwt1_t,
    float4* __restrict__ zbase) {
  const int bx = blockIdx.x;
  const int tid = threadIdx.x;
  {
    const size_t base = (size_t)bx * ZSTRIDE;
    const float4 z = {0.f, 0.f, 0.f, 0.f};
    for (size_t i = base + tid; i < base + ZSTRIDE && i < ZERO_F4; i += 320)
      zbase[i] = z;
  }
  if (bx >= 66) {  // lw -> lwT1 (transpose + bf16)
    if (tid < 256) {
      const int k = bx - 66;
      const int br = k / 232, j = k - br * 232;
      const float* src = br ? lwt : lwe;
      u16* dst = br ? lwt1_t : lwt1_e;
      const int e = j * 1024 + tid * 4;   // 232*1024 = 237,568
      const int h = e >> 12;              // /4096
      const int rem = e & 4095;
      const int n = rem >> 6, c = rem & 63;
      const float* s = src + (size_t)n * 3712 + (size_t)c * 58 + h;
      const float v0 = s[0], v1 = s[58], v2 = s[116], v3 = s[174];
      *(u32*)&dst[e] = f2bf_pk(v0, v1);
      *(u32*)&dst[e + 2] = f2bf_pk(v2, v3);
    }
    return;
  }
  if (bx >= 64) {  // gi_bias
    const int br = bx - 64;
    const float* wih = br ? wih_t : wih_e;
    const float* bih = br ? bih_t : bih_e;
    const float* lb = br ? lb_t : lb_e;
    float* bias2 = br ? bias2_t : bias2_e;
    __shared__ float s_lb[64];
    if (tid < 64) s_lb[tid] = lb[tid];
    __syncthreads();
    if (tid < 192) {
      float acc = bih[tid];
      const float* wr = wih + tid * 64;
      for (int d = 0; d < 64; ++d) acc = fmaf(wr[d], s_lb[d], acc);
      bias2[tid] = acc;
    }
    return;
  }
  // compose12
  const int br = bx >> 5;
  const float* w1 = br ? w1t : w1e;
  const float* b1 = br ? b1t : b1e;
  const float* w2 = br ? w2t : w2e;
  const float* b2 = br ? b2t : b2e;
  float* w12p = br ? w12p_t : w12p_e;
  float* b12o = br ? b12o_t : b12o_e;
  const int c12 = bx & 31;
  __shared__ float s_w1pad[16 * 169];
  __shared__ float s_w2c[400];
  __shared__ float s_b1[16];
  for (int i = tid; i < 2704; i += 320) s_w1pad[i] = 0.f;
  if (tid < 16) s_b1[tid] = b1[tid];
  __syncthreads();
  for (int i = tid; i < 400; i += 320) {
    const int c1 = i / 25, r = (i % 25) / 5, cc = i % 5;
    s_w1pad[c1 * 169 + (r + 4) * 13 + (cc + 4)] = w1[i];
    s_w2c[i] = w2[c12 * 400 + i];
  }
  __syncthreads();
  if (tid < 289) {
    const int py = tid / 17, px = tid % 17;
    float v = 0.f;
    if (py >= 4 && py <= 12 && px >= 4 && px <= 12) {
      const int sy = py - 4, sx = px - 4;
      float accs[2] = {0.f, 0.f};
      for (int c1 = 0; c1 < 16; ++c1) {
        const float* w2p = s_w2c + c1 * 25;
        const float* w1p = s_w1pad + c1 * 169 + (sy + 4) * 13 + (sx + 4);
#pragma unroll
        for (int uy = 0; uy < 5; ++uy)
#pragma unroll
          for (int ux = 0; ux < 5; ++ux)
            accs[uy & 1] = fmaf(w2p[uy * 5 + ux], w1p[-(uy * 13) - ux], accs[uy & 1]);
      }
      v = accs[0] + accs[1];
    }
    w12p[c12 * 289 + tid] = v;
  } else if (tid == 300) {
    float acc = b2[c12];
    for (int c1 = 0; c1 < 16; ++c1) {
      float sw = 0.f;
      for (int u = 0; u < 25; ++u) sw += s_w2c[c1 * 25 + u];
      acc = fmaf(sw, s_b1[c1], acc);
    }
    b12o[c12] = acc;
  }
}

// ---------------------------------------------------------------------------
// compose_weff: 4 parity layouts wkx[(p*13+kx)*64+o][16] bf16 (slot ky+p).
// ---------------------------------------------------------------------------
__global__ __launch_bounds__(256) void compose_weff_kernel(
    const float* __restrict__ w3e, const float* __restrict__ b3e,
    const float* __restrict__ w3t, const float* __restrict__ b3t,
    const float* __restrict__ w12p_e, const float* __restrict__ w12p_t,
    const float* __restrict__ b12_e, const float* __restrict__ b12_t,
    u16* __restrict__ wkx_e, u16* __restrict__ wkx_t,
    float* __restrict__ beff_e, float* __restrict__ beff_t) {
  const int br = blockIdx.y;
  const float* w3 = br ? w3t : w3e;
  const float* b3 = br ? b3t : b3e;
  const float* w12p = br ? w12p_t : w12p_e;
  const float* b12 = br ? b12_t : b12_e;
  u16* wkx = br ? wkx_t : wkx_e;
  float* beff = br ? beff_t : beff_e;
  const int o = blockIdx.x;
  __shared__ float s_pad[32 * 289];
  __shared__ float s_w3o[800];
  __shared__ float s_b12[32];
  const int tid = threadIdx.x;
  for (int i = tid; i < 9248; i += 256) s_pad[i] = w12p[i];
  for (int i = tid; i < 800; i += 256) s_w3o[i] = w3[o * 800 + i];
  if (tid < 32) s_b12[tid] = b12[tid];
  __syncthreads();
  if (tid < 169) {
    const int sy = tid / 13, sx = tid % 13;
    float accs[4] = {0.f, 0.f, 0.f, 0.f};
#pragma unroll 4
    for (int c = 0; c < 32; ++c) {
      const float* w3p = s_w3o + c * 25;
      const float* wp = s_pad + c * 289 + (sy + 4) * 17 + (sx + 4);
#pragma unroll
      for (int uy = 0; uy < 5; ++uy)
#pragma unroll
        for (int ux = 0; ux < 5; ++ux)
          accs[c & 3] = fmaf(w3p[uy * 5 + ux], wp[-(uy * 17) - ux], accs[c & 3]);
    }
    const u16 v = f2bf(accs[0] + accs[1] + accs[2] + accs[3]);
#pragma unroll
    for (int p = 0; p < 4; ++p)
      wkx[((p * 13 + sx) * 64 + o) * 16 + sy + p] = v;
  } else if (tid < 169 + 156) {  // 13 kx x 12 zero-slots
    const int t = tid - 169, kx = t / 12, q = t % 12;
    const int p = q / 3, idx = q % 3;
    const int slot = (idx < p) ? idx : (p + 13) + (idx - p);
    wkx[((p * 13 + kx) * 64 + o) * 16 + slot] = 0;
  }
  if (tid == 255) {
    float acc = b3[o];
    for (int c = 0; c < 32; ++c) {
      float sw = 0.f;
      for (int u = 0; u < 25; ++u) sw += s_w3o[c * 25 + u];
      acc = fmaf(sw, s_b12[c], acc);
    }
    beff[o] = acc;
  }
}

// ---------------------------------------------------------------------------
// FUSED conv13x13 + maxpool + linear, R18: 3-barrier phase structure.
// Wave tile = (chalf=wave&1, thalf=wave>>1), 32c x 32t x BOTH parities.
// Per by: s_x load -> BAR -> conv 52 MFMA (4 indep 13-chains; pairmax
// in-register, 16 scalar writes to pairmaxed s_m01[hh]) -> BAR -> pool
// (3x b128 reads + 5-window max, both hh) -> BAR -> linear 8 MFMA with
// prefetched bb[2][4]. accL accumulated across all (by,hh); ONE atomic
// epilogue per block. grid (34, 10, 8); tmpl cb>=1024 exit. LDS 40KB.
// ---------------------------------------------------------------------------
__global__ __launch_bounds__(256, 2) void conv_pool_lin_kernel(
    const float* __restrict__ xe, const u16* __restrict__ wkx_e,
    const float* __restrict__ beff_e, const u16* __restrict__ lwt1_e,
    float* __restrict__ lin_e,
    const float* __restrict__ xt, const u16* __restrict__ wkx_t,
    const float* __restrict__ beff_t, const u16* __restrict__ lwt1_t,
    float* __restrict__ lin_t) {
  const int zz = blockIdx.z;
  const bool ev = zz < 4;
  const int b = ev ? zz : zz - 4;
  const int W = ev ? 2048 : 1040;
  const int T = ev ? 2032 : 1024;
  const int cb = blockIdx.x * 60;
  if (cb >= T) return;
  const float* x = ev ? xe : xt;
  const u16* wkx = ev ? wkx_e : wkx_t;
  const float* beff = ev ? beff_e : beff_t;
  const u16* lwt1 = ev ? lwt1_e : lwt1_t;
  float* lin = ev ? lin_e : lin_t;

  __shared__ __align__(16) u16 s_x[80 * 24];        // 3840 B
  __shared__ __align__(16) u16 s_m01[2][64 * 72];   // 18432 B (pairmaxed [hh][c][t])
  __shared__ __align__(16) u16 s_poolT[2][64 * 72]; // 18432 B ([hh][t][c])
  __shared__ float s_beff[64];                      // total 40.2 KB

  const int tid = threadIdx.x;
  const int lane = tid & 63, wave = tid >> 6;
  const int cm = (wave & 1) * 32, tm = (wave >> 1) * 32;  // conv tile
  const int l31 = lane & 31, g8 = (lane >> 5) * 8;
  const int th = (wave & 1) * 32, nh = (wave >> 1) * 32;  // linear tile

  if (tid < 64) s_beff[tid] = beff[tid];  // consumed after later barriers

  const int by0 = blockIdx.y * 3;
  const int by1 = (by0 + 3 < 29) ? (by0 + 3) : 29;

  f32x16 accL = {};
  for (int by = by0; by < by1; ++by) {
    const int r0 = 4 * by;
    // s_x overwrite safe: prior-iter conv reads completed >=2 barriers ago.
    {
      const float* xb = x + ((size_t)b * 128 + r0) * W;
      for (int i = tid; i < 640; i += 256) {
        const int pr = i / 80, c = i - pr * 80;
        int gc = cb + c;
        if (gc > W - 1) gc = W - 1;
        *(u32*)&s_x[c * 24 + 2 * pr] =
            f2bf_pk(xb[(size_t)(2 * pr) * W + gc], xb[(size_t)(2 * pr + 1) * W + gc]);
      }
    }
    // prefetch linear B-fragments for both h (T14: issue early, LDS-indep)
    bf16x8 bb[2][4];
#pragma unroll
    for (int hh = 0; hh < 2; ++hh) {
      const u16* bp2 = lwt1 + ((size_t)((2 * by + hh) * 64 + nh + l31)) * 64 + g8;
#pragma unroll
      for (int ks = 0; ks < 4; ++ks) bb[hh][ks] = *(const bf16x8*)(bp2 + ks * 16);
    }
    __syncthreads();  // s_x ready
    // conv: both parities per wave, both hh -> 4 independent 13-chains.
#pragma unroll
    for (int hh = 0; hh < 2; ++hh) {
      const u16* aw0 = wkx + (((2 * hh) * 13) * 64 + cm + l31) * 16 + g8;
      const u16* aw1 = wkx + (((2 * hh + 1) * 13) * 64 + cm + l31) * 16 + g8;
      f32x16 a0 = {}, a1 = {};
      const u16* bxp = s_x + g8 + tm * 24;
#pragma unroll
      for (int kx = 0; kx < 13; ++kx) {
        const bf16x8 bvec = *(const bf16x8*)(bxp + (l31 + kx) * 24);
        const bf16x8 w0 = *(const bf16x8*)(aw0 + kx * 1024);
        const bf16x8 w1 = *(const bf16x8*)(aw1 + kx * 1024);
        a0 = __builtin_amdgcn_mfma_f32_32x32x16_bf16(w0, bvec, a0, 0, 0, 0);
        a1 = __builtin_amdgcn_mfma_f32_32x32x16_bf16(w1, bvec, a1, 0, 0, 0);
      }
      // in-register pairmax (bit-exact vs bf16-then-max: f2bf is monotone)
#pragma unroll
      for (int r = 0; r < 16; ++r) {
        const int c = cm + (r & 3) + 8 * (r >> 2) + (g8 >> 1);
        s_m01[hh][c * 72 + tm + l31] = f2bf(fmaxf(a0[r], a1[r]));
      }
    }
    __syncthreads();  // s_m01 ready; prior linear reads of s_poolT done
    // pool: 5-window max over t, both hh
    {
      const int pc = tid & 63, tg = tid >> 6;
      const int t0 = tg * 16;  // 0,16,32,48
      const float bias = s_beff[pc];
#pragma unroll
      for (int hh = 0; hh < 2; ++hh) {
        const u16* rp = &s_m01[hh][pc * 72 + t0];
        const u16x8 v0 = *(const u16x8*)(rp);
        const u16x8 v1 = *(const u16x8*)(rp + 8);
        const u16x8 v2 = *(const u16x8*)(rp + 16);
        float mv[20];
#pragma unroll
        for (int j = 0; j < 8; ++j) {
          mv[j] = bf2f(v0[j]);
          mv[j + 8] = bf2f(v1[j]);
          if (j < 4) mv[j + 16] = bf2f(v2[j]);
        }
#pragma unroll
        for (int i = 0; i < 16; ++i) {
          if (t0 + i < 60) {  // wave-uniform tail guard (tg==3 -> 12 outputs)
            float m = mv[i];
#pragma unroll
            for (int k = 1; k < 5; ++k) m = fmaxf(m, mv[i + k]);
            s_poolT[hh][(t0 + i) * 72 + pc] = f2bf(m + bias);
          }
        }
      }
    }
    __syncthreads();  // s_poolT ready
    // linear: accL[t][n] += sum_c poolT[h][t][c] * lwT1[h][n][c]
#pragma unroll
    for (int hh = 0; hh < 2; ++hh) {
      const u16* ap2 = &s_poolT[hh][(th + l31) * 72 + g8];
#pragma unroll
      for (int ks = 0; ks < 4; ++ks) {
        const bf16x8 a = *(const bf16x8*)(ap2 + ks * 16);
        accL = __builtin_amdgcn_mfma_f32_32x32x16_bf16(a, bb[hh][ks], accL, 0, 0, 0);
      }
    }
  }
  // coalesced atomic epilogue: col(lane) = n, row = t (ONE per block)
  {
    const int nn = nh + l31;
#pragma unroll
    for (int r = 0; r < 16; ++r) {
      const int t = th + (r & 3) + 8 * (r >> 2) + (g8 >> 1);
      const int tt = cb + t;
      if (t < 60 && tt < T)
        atomicAdd(&lin[((size_t)b * T + tt) * 64 + nn], accL[r]);
    }
  }
}

// ---------------------------------------------------------------------------
// gi GEMM, both branches: grid (191, 3); N=192, K=64.
// ---------------------------------------------------------------------------
__global__ __launch_bounds__(256) void gemm_gi_kernel(
    const float* __restrict__ Ae, const float* __restrict__ Wte,
    const float* __restrict__ biase, float* __restrict__ oute,
    const float* __restrict__ At, const float* __restrict__ Wtt,
    const float* __restrict__ biast, float* __restrict__ outt) {
  const int bx = blockIdx.x;
  const bool ev = bx < 127;
  const float* A = ev ? Ae : At;
  const float* Wt = ev ? Wte : Wtt;
  const float* bias = ev ? biase : biast;
  float* out = ev ? oute : outt;
  const int r0 = (ev ? bx : bx - 127) * 64;
  const int N = 192, K = 64;
  __shared__ float sA[64 * 33];
  __shared__ float sB[64 * 33];
  const int tid = threadIdx.x;
  const int n0 = blockIdx.y * 64;
  const int ty = tid >> 4, tx = tid & 15;
  float acc[4][4] = {};
  for (int kc = 0; kc < K; kc += 32) {
    __syncthreads();
#pragma unroll
    for (int rep = 0; rep < 8; ++rep) {
      const int l = tid + rep * 256;
      const int row = l >> 5, kk = l & 31;
      sA[row * 33 + kk] = A[(size_t)(r0 + row) * K + kc + kk];
      sB[row * 33 + kk] = Wt[(size_t)(n0 + row) * K + kc + kk];
    }
    __syncthreads();
#pragma unroll 8
    for (int kk = 0; kk < 32; ++kk) {
      const float a0 = sA[(ty * 4 + 0) * 33 + kk];
      const float a1 = sA[(ty * 4 + 1) * 33 + kk];
      const float a2 = sA[(ty * 4 + 2) * 33 + kk];
      const float a3 = sA[(ty * 4 + 3) * 33 + kk];
      const float b0 = sB[(tx * 4 + 0) * 33 + kk];
      const float b1 = sB[(tx * 4 + 1) * 33 + kk];
      const float b2 = sB[(tx * 4 + 2) * 33 + kk];
      const float b3 = sB[(tx * 4 + 3) * 33 + kk];
      acc[0][0] = fmaf(a0, b0, acc[0][0]); acc[0][1] = fmaf(a0, b1, acc[0][1]);
      acc[0][2] = fmaf(a0, b2, acc[0][2]); acc[0][3] = fmaf(a0, b3, acc[0][3]);
      acc[1][0] = fmaf(a1, b0, acc[1][0]); acc[1][1] = fmaf(a1, b1, acc[1][1]);
      acc[1][2] = fmaf(a1, b2, acc[1][2]); acc[1][3] = fmaf(a1, b3, acc[1][3]);
      acc[2][0] = fmaf(a2, b0, acc[2][0]); acc[2][1] = fmaf(a2, b1, acc[2][1]);
      acc[2][2] = fmaf(a2, b2, acc[2][2]); acc[2][3] = fmaf(a2, b3, acc[2][3]);
      acc[3][0] = fmaf(a3, b0, acc[3][0]); acc[3][1] = fmaf(a3, b1, acc[3][1]);
      acc[3][2] = fmaf(a3, b2, acc[3][2]); acc[3][3] = fmaf(a3, b3, acc[3][3]);
    }
  }
#pragma unroll
  for (int i = 0; i < 4; ++i)
#pragma unroll
    for (int j = 0; j < 4; ++j)
      out[(size_t)(r0 + ty * 4 + i) * N + n0 + tx * 4 + j] =
          acc[i][j] + bias[n0 + tx * 4 + j];
}

// ---------------------------------------------------------------------------
// GRU, both branches (grid 191). fp32 xy + bf16 xy_bf; logits (eval);
// t^T bf16 scatter (template).
// ---------------------------------------------------------------------------
__global__ __launch_bounds__(256) void gru_rec_kernel(
    float* __restrict__ xyE, const float* __restrict__ giE,
    const float* __restrict__ whhE, const float* __restrict__ bhhE,
    float* __restrict__ xyT, const float* __restrict__ giT,
    const float* __restrict__ whhT, const float* __restrict__ bhhT,
    u16* __restrict__ xybfE, u16* __restrict__ xybfT, u16* __restrict__ ttbf,
    const float* __restrict__ a_w, const float* __restrict__ a_b,
    float* __restrict__ logits) {
  const int bxid = blockIdx.x;
  const bool ev = bxid < 127;
  float* xy = ev ? xyE : xyT;
  u16* xybf = ev ? xybfE : xybfT;
  const float* gi = ev ? giE : giT;
  const float* whh = ev ? whhE : whhT;
  const float* bhh = ev ? bhhE : bhhT;
  const int T = ev ? 2032 : 1024;
  const int t0 = (ev ? bxid : bxid - 127) * 16;
  __shared__ float s_whh_t[64 * 192];
  __shared__ float s_h[16][64];
  __shared__ float s_aw[64];
  const int tid = threadIdx.x;
  const int lane = tid & 63, wave = tid >> 6;
  for (int i = tid; i < 192 * 64; i += 256) {
    const int j = i >> 6, d = i & 63;
    s_whh_t[d * 192 + j] = whh[i];
  }
  for (int i = tid; i < 16 * 64; i += 256) (&s_h[0][0])[i] = 0.f;
  if (tid < 64) s_aw[tid] = a_w[tid];
  const float ab = a_b[0];
  const float bhr = bhh[lane], bhz = bhh[64 + lane], bhn = bhh[128 + lane];
  __syncthreads();
  for (int b = 0; b < 4; ++b) {
    float gir[4], giz[4], gin[4];
#pragma unroll
    for (int sl = 0; sl < 4; ++sl) {
      int t = t0 + wave * 4 + sl; if (t > T - 1) t = T - 1;
      const float* girow = gi + ((size_t)b * T + t) * 192;
      gir[sl] = girow[lane]; giz[sl] = girow[64 + lane]; gin[sl] = girow[128 + lane];
    }
    float ahr[4] = {}, ahz[4] = {}, ahn[4] = {};
    for (int d = 0; d < 64; ++d) {
      const float wr_ = s_whh_t[d * 192 + lane];
      const float wz_ = s_whh_t[d * 192 + 64 + lane];
      const float wn_ = s_whh_t[d * 192 + 128 + lane];
#pragma unroll
      for (int sl = 0; sl < 4; ++sl) {
        const float hv = s_h[wave * 4 + sl][d];
        ahr[sl] = fmaf(wr_, hv, ahr[sl]);
        ahz[sl] = fmaf(wz_, hv, ahz[sl]);
        ahn[sl] = fmaf(wn_, hv, ahn[sl]);
      }
    }
    float hn[4];
#pragma unroll
    for (int sl = 0; sl < 4; ++sl) {
      const float r = 1.f / (1.f + __expf(-(gir[sl] + ahr[sl] + bhr)));
      const float z = 1.f / (1.f + __expf(-(giz[sl] + ahz[sl] + bhz)));
      const float n = tanhf(gin[sl] + r * (ahn[sl] + bhn));
      hn[sl] = (1.f - z) * n + z * s_h[wave * 4 + sl][lane];
    }
    __syncthreads();
#pragma unroll
    for (int sl = 0; sl < 4; ++sl) {
      const int t = t0 + wave * 4 + sl;
      s_h[wave * 4 + sl][lane] = hn[sl];
      if (t < T) {
        const size_t idx = ((size_t)b * T + t) * 64 + lane;
        xy[idx] = hn[sl];
        xybf[idx] = f2bf(hn[sl]);
        if (ev) {
          float v = hn[sl] * s_aw[lane];
#pragma unroll
          for (int off = 32; off > 0; off >>= 1) v += __shfl_down(v, off, 64);
          if (lane == 0) logits[b * 2032 + t] = v + ab;
        } else {
          ttbf[((size_t)b * 64 + lane) * 1024 + t] = f2bf(hn[sl]);
        }
      }
    }
    __syncthreads();
  }
}

// ---------------------------------------------------------------------------
// scores: P'[b,tau,eps] = exp(sum_d t[tau,d] e[eps,d]) + per-tau rowsums.
// |s| <= 64 so exp never overflows. grid (16,16,4).
// ---------------------------------------------------------------------------
__global__ __launch_bounds__(256) void scores_mfma_kernel(
    const u16* __restrict__ tbf, const u16* __restrict__ ebf,
    u16* __restrict__ P, float* __restrict__ rowsum) {
  __shared__ __align__(16) u16 sA[64 * 72];
  __shared__ __align__(16) u16 sB[128 * 72];
  const int tid = threadIdx.x;
  const int b = blockIdx.z;
  const int tau0 = blockIdx.x * 64;
  const int e0 = blockIdx.y * 128;
  const int lane = tid & 63, wave = tid >> 6;
  const int l31 = lane & 31, g8 = (lane >> 5) * 8;
  {
    const int row = tid >> 2, seg = (tid & 3) * 16;
    const u16* ap = &tbf[((size_t)b * 1024 + tau0 + row) * 64 + seg];
    u16* da = &sA[row * 72 + seg];
    *(u16x8*)da = *(const u16x8*)ap;
    *(u16x8*)(da + 8) = *(const u16x8*)(ap + 8);
  }
#pragma unroll
  for (int r = 0; r < 4; ++r) {
    const int q = tid + r * 256;
    const int row = q >> 3, seg = (q & 7) * 8;
    int eps = e0 + row; if (eps > 2031) eps = 2031;
    *(u16x8*)&sB[row * 72 + seg] =
        *(const u16x8*)&ebf[((size_t)b * 2032 + eps) * 64 + seg];
  }
  __syncthreads();
  const int mh = (wave & 1) * 32;
  const int nq = (wave >> 1) * 64;
  f32x16 acc0 = {}, acc1 = {};
#pragma unroll
  for (int ks = 0; ks < 4; ++ks) {
    bf16x8 a = *(const bf16x8*)&sA[(mh + l31) * 72 + ks * 16 + g8];
    bf16x8 b0 = *(const bf16x8*)&sB[(nq + l31) * 72 + ks * 16 + g8];
    bf16x8 b1 = *(const bf16x8*)&sB[(nq + 32 + l31) * 72 + ks * 16 + g8];
    acc0 = __builtin_amdgcn_mfma_f32_32x32x16_bf16(a, b0, acc0, 0, 0, 0);
    acc1 = __builtin_amdgcn_mfma_f32_32x32x16_bf16(a, b1, acc1, 0, 0, 0);
  }
  const int ep0 = e0 + nq + l31;
  const int ep1 = ep0 + 32;
#pragma unroll
  for (int r = 0; r < 16; ++r) {
    const int tau = tau0 + mh + (r & 3) + 8 * (r >> 2) + (g8 >> 1);
    const size_t prow = ((size_t)b * 1024 + tau) * 2032;
    const float e0v = __expf(acc0[r]);
    const float e1v = __expf(acc1[r]);
    float part = 0.f;
    if (ep0 < 2032) { P[prow + ep0] = f2bf(e0v); part += e0v; }
    if (ep1 < 2032) { P[prow + ep1] = f2bf(e1v); part += e1v; }
#pragma unroll
    for (int off = 16; off > 0; off >>= 1) part += __shfl_down(part, off, 32);
    if (l31 == 0) atomicAdd(&rowsum[b * 1024 + tau], part);
  }
}

// ---------------------------------------------------------------------------
// pv on bf16 MFMA with folded softmax normalization (1/rowsum applied in
// the P^T LDS transpose). grid (32, 4, 4); atomic f32 epilogue.
// ---------------------------------------------------------------------------
__global__ __launch_bounds__(256) void pv_mfma_kernel(
    const u16* __restrict__ P, const u16* __restrict__ ttbf,
    const float* __restrict__ rowsum, float* __restrict__ PV) {
  __shared__ __align__(16) u16 sPT[64 * 72];  // [eps][tau], pre-normalized
  __shared__ __align__(16) u16 sTT[64 * 72];  // [d][tau]
  const int tid = threadIdx.x;
  const int b = blockIdx.z;
  const int e0 = blockIdx.x * 64;
  const int tau_base = blockIdx.y * 256;
  const int lane = tid & 63, wave = tid >> 6;
  const int l31 = lane & 31, g8 = (lane >> 5) * 8;
  const int mh = (wave & 1) * 32, nh = (wave >> 1) * 32;
  f32x16 acc = {};
  for (int cc = 0; cc < 4; ++cc) {
    const int tc = tau_base + cc * 64;
    __syncthreads();
#pragma unroll
    for (int k = 0; k < 2; ++k) {
      const int q = tid + k * 256;
      const int row = q >> 3, seg = (q & 7) * 8;
      const float inv = 1.0f / rowsum[b * 1024 + tc + row];
      int er = e0 + seg;
      if (er > 2032 - 8) er = 2032 - 8;
      const u16x8 v = *(const u16x8*)&P[((size_t)b * 1024 + tc + row) * 2032 + er];
#pragma unroll
      for (int j = 0; j < 8; ++j)
        sPT[(seg + j) * 72 + row] = f2bf(bf2f(v[j]) * inv);
    }
#pragma unroll
    for (int k = 0; k < 2; ++k) {
      const int q = tid + k * 256;
      const int row = q >> 3, seg = (q & 7) * 8;
      *(u16x8*)&sTT[row * 72 + seg] =
          *(const u16x8*)&ttbf[((size_t)b * 64 + row) * 1024 + tc + seg];
    }
    __syncthreads();
#pragma unroll
    for (int ks = 0; ks < 4; ++ks) {
      bf16x8 a = *(const bf16x8*)&sPT[(mh + l31) * 72 + ks * 16 + g8];
      bf16x8 bb = *(const bf16x8*)&sTT[(nh + l31) * 72 + ks * 16 + g8];
      acc = __builtin_amdgcn_mfma_f32_32x32x16_bf16(a, bb, acc, 0, 0, 0);
    }
  }
#pragma unroll
  for (int r = 0; r < 16; ++r) {
    const int eps = e0 + mh + (r & 3) + 8 * (r >> 2) + (g8 >> 1);
    if (eps < 2032)
      atomicAdd(&PV[((size_t)b * 2032 + eps) * 64 + nh + l31], acc[r]);
  }
}

// ---------------------------------------------------------------------------
// red_reduce with fused att softmax (per-block redundant softmax of logits).
// grid (16, 4).
// ---------------------------------------------------------------------------
__global__ __launch_bounds__(256) void red_reduce_kernel(
    const float* __restrict__ emat, const float* __restrict__ PV,
    const float* __restrict__ logits, float* __restrict__ red) {
  __shared__ float s_att[2032];
  __shared__ float sred[4];
  __shared__ float s_part[4][64];
  const int tid = threadIdx.x;
  const int lane = tid & 63, wave = tid >> 6;
  const int b = blockIdx.y;
  float m = -3.4e38f;
  for (int i = tid; i < 2032; i += 256) {
    const float v = logits[b * 2032 + i];
    s_att[i] = v;
    m = fmaxf(m, v);
  }
#pragma unroll
  for (int off = 32; off > 0; off >>= 1) m = fmaxf(m, __shfl_down(m, off, 64));
  if (lane == 0) sred[wave] = m;
  __syncthreads();
  m = fmaxf(fmaxf(sred[0], sred[1]), fmaxf(sred[2], sred[3]));
  __syncthreads();
  float ssum = 0.f;
  for (int i = tid; i < 2032; i += 256) {
    const float v = __expf(s_att[i] - m);
    s_att[i] = v;
    ssum += v;
  }
#pragma unroll
  for (int off = 32; off > 0; off >>= 1) ssum += __shfl_down(ssum, off, 64);
  if (lane == 0) sred[wave] = ssum;
  __syncthreads();
  const float inv = 1.f / (sred[0] + sred[1] + sred[2] + sred[3]);
  const int i0 = blockIdx.x * 127;
  float acc = 0.f;
  for (int i = i0 + wave; i < i0 + 127; i += 4) {
    const size_t idx = ((size_t)b * 2032 + i) * 64 + lane;
    acc = fmaf(fabsf(PV[idx] - emat[idx]), s_att[i], acc);
  }
  s_part[wave][lane] = acc;
  __syncthreads();
  if (tid < 64)
    atomicAdd(&red[b * 64 + tid],
              (s_part[0][tid] + s_part[1][tid] + s_part[2][tid] + s_part[3][tid]) * inv);
}

// ---------------------------------------------------------------------------
// mlp: h = relu(red@h_w^T + h_b); out = softmax(h@c_w^T + c_b). grid 4.
// ---------------------------------------------------------------------------
__global__ __launch_bounds__(128) void mlp_kernel(
    const float* __restrict__ red, const float* __restrict__ h_w,
    const float* __restrict__ h_b, const float* __restrict__ c_w,
    const float* __restrict__ c_b, float* __restrict__ out) {
  __shared__ float s_red[64];
  __shared__ float s_hv[128];
  const int tid = threadIdx.x;
  const int b = blockIdx.x;
  if (tid < 64) s_red[tid] = red[b * 64 + tid];
  __syncthreads();
  {
    float acc = h_b[tid];
    const float* hw = h_w + tid * 64;
    for (int d = 0; d < 64; ++d) acc = fmaf(s_red[d], hw[d], acc);
    s_hv[tid] = fmaxf(acc, 0.f);
  }
  __syncthreads();
  if (tid == 0) {
    float l0 = c_b[0], l1 = c_b[1];
    for (int j = 0; j < 128; ++j) {
      l0 = fmaf(s_hv[j], c_w[j], l0);
      l1 = fmaf(s_hv[j], c_w[128 + j], l1);
    }
    const float mm = fmaxf(l0, l1);
    const float e0 = __expf(l0 - mm), e1 = __expf(l1 - mm);
    const float invs = 1.f / (e0 + e1);
    out[b * 2 + 0] = e0 * invs;
    out[b * 2 + 1] = e1 * invs;
  }
}

// ===========================================================================
extern "C" void kernel_launch(void* const* d_in, const int* in_sizes, int n_in,
                              void* d_out, int out_size, void* d_ws, size_t ws_size,
                              hipStream_t stream) {
  const float* evaluation = (const float*)d_in[0];
  const float* templ      = (const float*)d_in[1];
  const float* e_w1 = (const float*)d_in[2];
  const float* e_b1 = (const float*)d_in[3];
  const float* e_w2 = (const float*)d_in[4];
  const float* e_b2 = (const float*)d_in[5];
  const float* e_w3 = (const float*)d_in[6];
  const float* e_b3 = (const float*)d_in[7];
  const float* el_w = (const float*)d_in[8];
  const float* el_b = (const float*)d_in[9];
  const float* eg_wih = (const float*)d_in[10];
  const float* eg_whh = (const float*)d_in[11];
  const float* eg_bih = (const float*)d_in[12];
  const float* eg_bhh = (const float*)d_in[13];
  const float* t_w1 = (const float*)d_in[14];
  const float* t_b1 = (const float*)d_in[15];
  const float* t_w2 = (const float*)d_in[16];
  const float* t_b2 = (const float*)d_in[17];
  const float* t_w3 = (const float*)d_in[18];
  const float* t_b3 = (const float*)d_in[19];
  const float* tl_w = (const float*)d_in[20];
  const float* tl_b = (const float*)d_in[21];
  const float* tg_wih = (const float*)d_in[22];
  const float* tg_whh = (const float*)d_in[23];
  const float* tg_bih = (const float*)d_in[24];
  const float* tg_bhh = (const float*)d_in[25];
  const float* a_w = (const float*)d_in[26];
  const float* a_b = (const float*)d_in[27];
  const float* h_w = (const float*)d_in[28];
  const float* h_b = (const float*)d_in[29];
  const float* c_w = (const float*)d_in[30];
  const float* c_b = (const float*)d_in[31];

  float* ws = (float*)d_ws;
  float* beff_e  = ws + OFF_BEFF_E;
  float* beff_t  = ws + OFF_BEFF_T;
  float* bias2_e = ws + OFF_BIAS2_E;
  float* bias2_t = ws + OFF_BIAS2_T;
  u16*   wkx_e   = (u16*)(ws + OFF_WKX_E);
  u16*   wkx_t   = (u16*)(ws + OFF_WKX_T);
  float* w12p_e  = ws + OFF_W12P_E;
  float* w12p_t  = ws + OFF_W12P_T;
  float* b12_e   = ws + OFF_B12_E;
  float* b12_t   = ws + OFF_B12_T;
  u16*   lwt1_e  = (u16*)(ws + OFF_LWT1_E);
  u16*   lwt1_t  = (u16*)(ws + OFF_LWT1_T);
  float* attbuf  = ws + OFF_ATT;
  u16*   xybf_e  = (u16*)(ws + OFF_XYBF_E);
  u16*   xybf_t  = (u16*)(ws + OFF_XYBF_T);
  u16*   ttbf    = (u16*)(ws + OFF_TTBF);
  float* lin_e   = ws + OFF_LIN_E;
  float* lin_t   = ws + OFF_LIN_T;
  float* PVbuf   = ws + OFF_PV;
  float* redbuf  = ws + OFF_RED;
  float* rsum    = ws + OFF_RSUM;
  float* gi_e    = ws + OFF_GI_E;
  float* gi_t    = ws + OFF_GI_T;
  u16*   Pbuf    = (u16*)(ws + OFF_P);

  // prep (zeroes lin/PV/red/rowsum + compose12 + gi_bias + lw->lwT1), weff
  prep_kernel<<<530, 320, 0, stream>>>(
      e_w1, e_b1, e_w2, e_b2, t_w1, t_b1, t_w2, t_b2, w12p_e, w12p_t, b12_e, b12_t,
      eg_wih, eg_bih, el_b, bias2_e, tg_wih, tg_bih, tl_b, bias2_t,
      el_w, tl_w, lwt1_e, lwt1_t, (float4*)lin_e);
  compose_weff_kernel<<<dim3(64, 2), 256, 0, stream>>>(
      e_w3, e_b3, t_w3, t_b3, w12p_e, w12p_t, b12_e, b12_t, wkx_e, wkx_t, beff_e, beff_t);

  // fused conv+pool+linear (3-barrier phases, atomic into lin), then GRU chain
  conv_pool_lin_kernel<<<dim3(34, 10, 8), 256, 0, stream>>>(
      evaluation, wkx_e, beff_e, lwt1_e, lin_e,
      templ, wkx_t, beff_t, lwt1_t, lin_t);
  gemm_gi_kernel<<<dim3(191, 3), 256, 0, stream>>>(
      lin_e, eg_wih, bias2_e, gi_e, lin_t, tg_wih, bias2_t, gi_t);
  gru_rec_kernel<<<191, 256, 0, stream>>>(
      lin_e, gi_e, eg_whh, eg_bhh, lin_t, gi_t, tg_whh, tg_bhh,
      xybf_e, xybf_t, ttbf, a_w, a_b, attbuf);

  // cross attention: exp-scores (+rowsum) -> normalized pv (softmax folded)
  scores_mfma_kernel<<<dim3(16, 16, 4), 256, 0, stream>>>(xybf_t, xybf_e, Pbuf, rsum);
  pv_mfma_kernel<<<dim3(32, 4, 4), 256, 0, stream>>>(Pbuf, ttbf, rsum, PVbuf);

  // head: (att softmax fused into) weighted reduce -> MLP
  red_reduce_kernel<<<dim3(16, 4), 256, 0, stream>>>(lin_e, PVbuf, attbuf, redbuf);
  mlp_kernel<<<4, 128, 0, stream>>>(redbuf, h_w, h_b, c_w, c_b, (float*)d_out);
}

// Round 6
// 305.877 us; speedup vs baseline: 1.2637x; 1.2637x over previous
//
#include <hip/hip_runtime.h>
#include <hip/hip_bf16.h>
#include <cmath>

// ============================================================================
// DeepTemplateMatchingModule on MI355X — round 19.
// R18 post-mortem: three f32x16 accs + bb[2][4] live across phases -> accL
// scratch round-trip each iter (WRITE 147MB). Pattern confirmed 4x: extended
// acc live ranges spill; clean variants all hit ~99us (R13/R16/R17 at occ
// 47/26/17%). R19: revert to R17-exact structure (clean, 99us) + the ONE
// untested lever: s_x staging latency. T14 consume-then-reissue — commit
// prefetched regs to LDS at iter top, issue next tile's global loads
// immediately (they fly across conv/pool/linear phases), single s_x buffer
// (conv reads complete before the s_out barrier => next-iter writes safe).
// Bounded downside: if hipcc drains vmcnt at __syncthreads, we equal R17.
// ============================================================================

typedef unsigned short u16;
typedef unsigned int u32;
typedef __attribute__((ext_vector_type(8))) short bf16x8;
typedef __attribute__((ext_vector_type(8))) unsigned short u16x8;
typedef __attribute__((ext_vector_type(16))) float f32x16;

__device__ __forceinline__ u16 f2bf(float f) {
  unsigned int x = __float_as_uint(f);
  return (u16)((x + 0x7fffu + ((x >> 16) & 1u)) >> 16);
}
__device__ __forceinline__ float bf2f(u16 v) {
  return __uint_as_float(((unsigned int)v) << 16);
}
__device__ __forceinline__ u32 f2bf_pk(float a, float b) {
  __hip_bfloat162 h = __float22bfloat162_rn(float2{a, b});
  u32 r;
  __builtin_memcpy(&r, &h, 4);  // low 16 = a, high 16 = b
  return r;
}

// ---- workspace layout (float offsets) ----
static const size_t OFF_BEFF_E  = 0;          // 64
static const size_t OFF_BEFF_T  = 64;
static const size_t OFF_BIAS2_E = 128;        // 192
static const size_t OFF_BIAS2_T = 320;
static const size_t OFF_WKX_E   = 512;        // 4 parities x 13x64x16 u16 = 26624 f
static const size_t OFF_WKX_T   = 27136;      // 26624 f
static const size_t OFF_W12P_E  = 53760;      // 9248
static const size_t OFF_W12P_T  = 63008;      // 9248
static const size_t OFF_B12_E   = 72256;      // 32
static const size_t OFF_B12_T   = 72288;      // 32
static const size_t OFF_LWT1_E  = 72320;      // lwT1[h][n][c] bf16: 237568 u16 = 118784 f
static const size_t OFF_LWT1_T  = 191104;     // 118784 f
static const size_t OFF_ATT     = 309888;     // 8128 f (raw logits)
static const size_t OFF_XYBF_E  = 318016;     // 260096 f (4x2032x64 u16)
static const size_t OFF_XYBF_T  = 578112;     // 131072 f (4x1024x64 u16)
static const size_t OFF_TTBF    = 709184;     // 131072 f (t^T: 4x64x1024 u16)
// contiguous zero region (zeroed by prep): lin_e, lin_t, PV, red, rowsum
static const size_t OFF_LIN_E   = 840256;     // 520192 f
static const size_t OFF_LIN_T   = 1360448;    // 262144 f
static const size_t OFF_PV      = 1622592;    // 520192 f
static const size_t OFF_RED     = 2142784;    // 256 f
static const size_t OFF_RSUM    = 2143040;    // 4096 f
static const size_t ZERO_F4     = 326720;     // 1,306,880 f / 4
static const size_t ZSTRIDE     = 617;        // 530 * 617 >= 326720
static const size_t OFF_GI_E    = 2147136;    // 1,560,576 f
static const size_t OFF_GI_T    = 3707712;    // 786,432 f
static const size_t OFF_P       = 4494144;    // u16: 8,323,072 u16 (4,161,536 f)

// ---------------------------------------------------------------------------
// prep: zero region + compose12 (bx<64) + gi_bias (64..65) + lw->lwT1 (>=66).
// lwT1[h][n][c] = bf16(lw[n][c*58+h]); 237,568 els per branch.
// ---------------------------------------------------------------------------
__global__ __launch_bounds__(320) void prep_kernel(
    const float* __restrict__ w1e, const float* __restrict__ b1e,
    const float* __restrict__ w2e, const float* __restrict__ b2e,
    const float* __restrict__ w1t, const float* __restrict__ b1t,
    const float* __restrict__ w2t, const float* __restrict__ b2t,
    float* __restrict__ w12p_e, float* __restrict__ w12p_t,
    float* __restrict__ b12o_e, float* __restrict__ b12o_t,
    const float* __restrict__ wih_e, const float* __restrict__ bih_e,
    const float* __restrict__ lb_e, float* __restrict__ bias2_e,
    const float* __restrict__ wih_t, const float* __restrict__ bih_t,
    const float* __restrict__ lb_t, float* __restrict__ bias2_t,
    const float* __restrict__ lwe, const float* __restrict__ lwt,
    u16* __restrict__ lwt1_e, u16* __restrict__ lwt1_t,
    float4* __restrict__ zbase) {
  const int bx = blockIdx.x;
  const int tid = threadIdx.x;
  {
    const size_t base = (size_t)bx * ZSTRIDE;
    const float4 z = {0.f, 0.f, 0.f, 0.f};
    for (size_t i = base + tid; i < base + ZSTRIDE && i < ZERO_F4; i += 320)
      zbase[i] = z;
  }
  if (bx >= 66) {  // lw -> lwT1 (transpose + bf16)
    if (tid < 256) {
      const int k = bx - 66;
      const int br = k / 232, j = k - br * 232;
      const float* src = br ? lwt : lwe;
      u16* dst = br ? lwt1_t : lwt1_e;
      const int e = j * 1024 + tid * 4;   // 232*1024 = 237,568
      const int h = e >> 12;              // /4096
      const int rem = e & 4095;
      const int n = rem >> 6, c = rem & 63;
      const float* s = src + (size_t)n * 3712 + (size_t)c * 58 + h;
      const float v0 = s[0], v1 = s[58], v2 = s[116], v3 = s[174];
      *(u32*)&dst[e] = f2bf_pk(v0, v1);
      *(u32*)&dst[e + 2] = f2bf_pk(v2, v3);
    }
    return;
  }
  if (bx >= 64) {  // gi_bias
    const int br = bx - 64;
    const float* wih = br ? wih_t : wih_e;
    const float* bih = br ? bih_t : bih_e;
    const float* lb = br ? lb_t : lb_e;
    float* bias2 = br ? bias2_t : bias2_e;
    __shared__ float s_lb[64];
    if (tid < 64) s_lb[tid] = lb[tid];
    __syncthreads();
    if (tid < 192) {
      float acc = bih[tid];
      const float* wr = wih + tid * 64;
      for (int d = 0; d < 64; ++d) acc = fmaf(wr[d], s_lb[d], acc);
      bias2[tid] = acc;
    }
    return;
  }
  // compose12
  const int br = bx >> 5;
  const float* w1 = br ? w1t : w1e;
  const float* b1 = br ? b1t : b1e;
  const float* w2 = br ? w2t : w2e;
  const float* b2 = br ? b2t : b2e;
  float* w12p = br ? w12p_t : w12p_e;
  float* b12o = br ? b12o_t : b12o_e;
  const int c12 = bx & 31;
  __shared__ float s_w1pad[16 * 169];
  __shared__ float s_w2c[400];
  __shared__ float s_b1[16];
  for (int i = tid; i < 2704; i += 320) s_w1pad[i] = 0.f;
  if (tid < 16) s_b1[tid] = b1[tid];
  __syncthreads();
  for (int i = tid; i < 400; i += 320) {
    const int c1 = i / 25, r = (i % 25) / 5, cc = i % 5;
    s_w1pad[c1 * 169 + (r + 4) * 13 + (cc + 4)] = w1[i];
    s_w2c[i] = w2[c12 * 400 + i];
  }
  __syncthreads();
  if (tid < 289) {
    const int py = tid / 17, px = tid % 17;
    float v = 0.f;
    if (py >= 4 && py <= 12 && px >= 4 && px <= 12) {
      const int sy = py - 4, sx = px - 4;
      float accs[2] = {0.f, 0.f};
      for (int c1 = 0; c1 < 16; ++c1) {
        const float* w2p = s_w2c + c1 * 25;
        const float* w1p = s_w1pad + c1 * 169 + (sy + 4) * 13 + (sx + 4);
#pragma unroll
        for (int uy = 0; uy < 5; ++uy)
#pragma unroll
          for (int ux = 0; ux < 5; ++ux)
            accs[uy & 1] = fmaf(w2p[uy * 5 + ux], w1p[-(uy * 13) - ux], accs[uy & 1]);
      }
      v = accs[0] + accs[1];
    }
    w12p[c12 * 289 + tid] = v;
  } else if (tid == 300) {
    float acc = b2[c12];
    for (int c1 = 0; c1 < 16; ++c1) {
      float sw = 0.f;
      for (int u = 0; u < 25; ++u) sw += s_w2c[c1 * 25 + u];
      acc = fmaf(sw, s_b1[c1], acc);
    }
    b12o[c12] = acc;
  }
}

// ---------------------------------------------------------------------------
// compose_weff: 4 parity layouts wkx[(p*13+kx)*64+o][16] bf16 (slot ky+p).
// ---------------------------------------------------------------------------
__global__ __launch_bounds__(256) void compose_weff_kernel(
    const float* __restrict__ w3e, const float* __restrict__ b3e,
    const float* __restrict__ w3t, const float* __restrict__ b3t,
    const float* __restrict__ w12p_e, const float* __restrict__ w12p_t,
    const float* __restrict__ b12_e, const float* __restrict__ b12_t,
    u16* __restrict__ wkx_e, u16* __restrict__ wkx_t,
    float* __restrict__ beff_e, float* __restrict__ beff_t) {
  const int br = blockIdx.y;
  const float* w3 = br ? w3t : w3e;
  const float* b3 = br ? b3t : b3e;
  const float* w12p = br ? w12p_t : w12p_e;
  const float* b12 = br ? b12_t : b12_e;
  u16* wkx = br ? wkx_t : wkx_e;
  float* beff = br ? beff_t : beff_e;
  const int o = blockIdx.x;
  __shared__ float s_pad[32 * 289];
  __shared__ float s_w3o[800];
  __shared__ float s_b12[32];
  const int tid = threadIdx.x;
  for (int i = tid; i < 9248; i += 256) s_pad[i] = w12p[i];
  for (int i = tid; i < 800; i += 256) s_w3o[i] = w3[o * 800 + i];
  if (tid < 32) s_b12[tid] = b12[tid];
  __syncthreads();
  if (tid < 169) {
    const int sy = tid / 13, sx = tid % 13;
    float accs[4] = {0.f, 0.f, 0.f, 0.f};
#pragma unroll 4
    for (int c = 0; c < 32; ++c) {
      const float* w3p = s_w3o + c * 25;
      const float* wp = s_pad + c * 289 + (sy + 4) * 17 + (sx + 4);
#pragma unroll
      for (int uy = 0; uy < 5; ++uy)
#pragma unroll
        for (int ux = 0; ux < 5; ++ux)
          accs[c & 3] = fmaf(w3p[uy * 5 + ux], wp[-(uy * 17) - ux], accs[c & 3]);
    }
    const u16 v = f2bf(accs[0] + accs[1] + accs[2] + accs[3]);
#pragma unroll
    for (int p = 0; p < 4; ++p)
      wkx[((p * 13 + sx) * 64 + o) * 16 + sy + p] = v;
  } else if (tid < 169 + 156) {  // 13 kx x 12 zero-slots
    const int t = tid - 169, kx = t / 12, q = t % 12;
    const int p = q / 3, idx = q % 3;
    const int slot = (idx < p) ? idx : (p + 13) + (idx - p);
    wkx[((p * 13 + kx) * 64 + o) * 16 + slot] = 0;
  }
  if (tid == 255) {
    float acc = b3[o];
    for (int c = 0; c < 32; ++c) {
      float sw = 0.f;
      for (int u = 0; u < 25; ++u) sw += s_w3o[c * 25 + u];
      acc = fmaf(sw, s_b12[c], acc);
    }
    beff[o] = acc;
  }
}

// ---------------------------------------------------------------------------
// FUSED conv13x13 + maxpool + linear, R19: R17 structure + T14 x-staging.
// Per iter: commit prefetched x regs to s_x -> issue next tile's loads
// (fly across conv/pool/linear) -> BAR -> per hh: wfrag[13]+bb[4] preload,
// conv 4 indep chains (kx 7/6 split), s_out (stride 72), pool 6x b128,
// linear 8 MFMA into accL. ONE atomic epilogue/block. grid (34, 10, 8).
// ---------------------------------------------------------------------------
__global__ __launch_bounds__(256, 2) void conv_pool_lin_kernel(
    const float* __restrict__ xe, const u16* __restrict__ wkx_e,
    const float* __restrict__ beff_e, const u16* __restrict__ lwt1_e,
    float* __restrict__ lin_e,
    const float* __restrict__ xt, const u16* __restrict__ wkx_t,
    const float* __restrict__ beff_t, const u16* __restrict__ lwt1_t,
    float* __restrict__ lin_t) {
  const int zz = blockIdx.z;
  const bool ev = zz < 4;
  const int b = ev ? zz : zz - 4;
  const int W = ev ? 2048 : 1040;
  const int T = ev ? 2032 : 1024;
  const int cb = blockIdx.x * 60;
  if (cb >= T) return;
  const float* x = ev ? xe : xt;
  const u16* wkx = ev ? wkx_e : wkx_t;
  const float* beff = ev ? beff_e : beff_t;
  const u16* lwt1 = ev ? lwt1_e : lwt1_t;
  float* lin = ev ? lin_e : lin_t;

  __shared__ __align__(16) u16 s_x[80 * 24];       // 3840 B
  __shared__ __align__(16) u16 s_out[2 * 64 * 72]; // 18432 B (stride 72: 16B rows)
  __shared__ __align__(16) u16 s_poolT[64 * 72];   // 9216 B ([t][c])
  __shared__ float s_beff[64];

  const int tid = threadIdx.x;
  const int lane = tid & 63, wave = tid >> 6;
  const int rsel = wave & 1, cm = (wave >> 1) * 32;
  const int l31 = lane & 31, g8 = (lane >> 5) * 8;
  const int th = (wave & 1) * 32, nh = (wave >> 1) * 32;

  if (tid < 64) s_beff[tid] = beff[tid];  // consumed after later barriers

  const int by0 = blockIdx.y * 3;
  const int by1 = (by0 + 3 < 29) ? (by0 + 3) : 29;

  // T14 register prefetch of the x staging rows (chunks i = tid + k*256)
  const int pr_ = tid < 384 ? ((tid & 127) + (tid >> 7) * 128) : 0;  // unused helper placeholder
  (void)pr_;
  float p0[3], p1[3];
  {
    const float* xb = x + ((size_t)b * 128 + 4 * by0) * W;
#pragma unroll
    for (int k = 0; k < 3; ++k) {
      const int i = tid + k * 256;
      if (i < 640) {
        const int pr = i / 80, c = i - pr * 80;
        int gc = cb + c;
        if (gc > W - 1) gc = W - 1;
        p0[k] = xb[(size_t)(2 * pr) * W + gc];
        p1[k] = xb[(size_t)(2 * pr + 1) * W + gc];
      }
    }
  }

  f32x16 accL = {};
  for (int by = by0; by < by1; ++by) {
    // commit prefetched x to LDS (safe: prior-iter conv reads of s_x
    // completed before that iter's s_out barrier).
#pragma unroll
    for (int k = 0; k < 3; ++k) {
      const int i = tid + k * 256;
      if (i < 640) {
        const int pr = i / 80, c = i - pr * 80;
        *(u32*)&s_x[c * 24 + 2 * pr] = f2bf_pk(p0[k], p1[k]);
      }
    }
    if (by + 1 < by1) {  // issue next tile's loads; overlap conv/pool/linear
      const float* xb = x + ((size_t)b * 128 + 4 * (by + 1)) * W;
#pragma unroll
      for (int k = 0; k < 3; ++k) {
        const int i = tid + k * 256;
        if (i < 640) {
          const int pr = i / 80, c = i - pr * 80;
          int gc = cb + c;
          if (gc > W - 1) gc = W - 1;
          p0[k] = xb[(size_t)(2 * pr) * W + gc];
          p1[k] = xb[(size_t)(2 * pr + 1) * W + gc];
        }
      }
    }
    __syncthreads();
#pragma unroll
    for (int hh = 0; hh < 2; ++hh) {
      const int p = 2 * hh + rsel;
      const int h = 2 * by + hh;
      // preload weights (L1-hot) and the linear's lwt1 fragments (T14: issue
      // early, consume after BAR2 — LDS-independent loads).
      bf16x8 wfrag[13];
      {
        const u16* aw = wkx + ((p * 13) * 64 + cm + l31) * 16 + g8;
#pragma unroll
        for (int kx = 0; kx < 13; ++kx) wfrag[kx] = *(const bf16x8*)(aw + kx * 1024);
      }
      bf16x8 bb[4];
      {
        const u16* bp2 = lwt1 + ((size_t)(h * 64 + nh + l31)) * 64 + g8;
#pragma unroll
        for (int ks = 0; ks < 4; ++ks) bb[ks] = *(const bf16x8*)(bp2 + ks * 16);
      }
      // conv: 4 independent accumulate chains, interleaved issue.
      f32x16 c0a = {}, c1a = {}, c0b = {}, c1b = {};
      const u16* bxp = s_x + g8;
#pragma unroll
      for (int kx = 0; kx < 6; ++kx) {
        bf16x8 b0 = *(const bf16x8*)(bxp + (l31 + kx) * 24);
        bf16x8 b1 = *(const bf16x8*)(bxp + (32 + l31 + kx) * 24);
        bf16x8 b0q = *(const bf16x8*)(bxp + (l31 + kx + 7) * 24);
        bf16x8 b1q = *(const bf16x8*)(bxp + (32 + l31 + kx + 7) * 24);
        c0a = __builtin_amdgcn_mfma_f32_32x32x16_bf16(wfrag[kx], b0, c0a, 0, 0, 0);
        c1a = __builtin_amdgcn_mfma_f32_32x32x16_bf16(wfrag[kx], b1, c1a, 0, 0, 0);
        c0b = __builtin_amdgcn_mfma_f32_32x32x16_bf16(wfrag[kx + 7], b0q, c0b, 0, 0, 0);
        c1b = __builtin_amdgcn_mfma_f32_32x32x16_bf16(wfrag[kx + 7], b1q, c1b, 0, 0, 0);
      }
      {  // kx = 6: a-chains only
        bf16x8 b0 = *(const bf16x8*)(bxp + (l31 + 6) * 24);
        bf16x8 b1 = *(const bf16x8*)(bxp + (32 + l31 + 6) * 24);
        c0a = __builtin_amdgcn_mfma_f32_32x32x16_bf16(wfrag[6], b0, c0a, 0, 0, 0);
        c1a = __builtin_amdgcn_mfma_f32_32x32x16_bf16(wfrag[6], b1, c1a, 0, 0, 0);
      }
#pragma unroll
      for (int r = 0; r < 16; ++r) {
        const int c = cm + (r & 3) + 8 * (r >> 2) + (g8 >> 1);
        u16* o = s_out + (rsel * 64 + c) * 72;
        const u32 pk = f2bf_pk(c0a[r] + c0b[r], c1a[r] + c1b[r]);
        o[l31] = (u16)pk;
        o[32 + l31] = (u16)(pk >> 16);
      }
      __syncthreads();  // s_out complete; prior GEMM reads of s_poolT done
      {
        const int pc = tid & 63, tg = tid >> 6;
        const int t0 = tg * 16;  // 0,16,32,48; outputs t0..min(t0+15,59)
        const float bias = s_beff[pc];
        const u16* r0p = s_out + pc * 72 + t0;
        const u16* r1p = s_out + (64 + pc) * 72 + t0;
        const u16x8 a0 = *(const u16x8*)(r0p);
        const u16x8 a1 = *(const u16x8*)(r0p + 8);
        const u16x8 a2 = *(const u16x8*)(r0p + 16);
        const u16x8 q0 = *(const u16x8*)(r1p);
        const u16x8 q1 = *(const u16x8*)(r1p + 8);
        const u16x8 q2 = *(const u16x8*)(r1p + 16);
        float m01[20];
#pragma unroll
        for (int j = 0; j < 8; ++j) {
          m01[j] = fmaxf(bf2f(a0[j]), bf2f(q0[j]));
          m01[j + 8] = fmaxf(bf2f(a1[j]), bf2f(q1[j]));
          if (j < 4) m01[j + 16] = fmaxf(bf2f(a2[j]), bf2f(q2[j]));
        }
#pragma unroll
        for (int i = 0; i < 16; ++i) {
          if (t0 + i < 60) {  // wave-uniform tail guard (tg==3 -> 12 outputs)
            float m = m01[i];
#pragma unroll
            for (int k = 1; k < 5; ++k) m = fmaxf(m, m01[i + k]);
            s_poolT[(t0 + i) * 72 + pc] = f2bf(m + bias);  // transposed (+bias)
          }
        }
      }
      __syncthreads();  // s_poolT complete
      // linear: accL[t][n] += sum_c poolT[t][c] * lwT1[h][n][c] (bb prefetched)
      {
        const u16* ap2 = s_poolT + (th + l31) * 72 + g8;
#pragma unroll
        for (int ks = 0; ks < 4; ++ks) {
          bf16x8 a = *(const bf16x8*)(ap2 + ks * 16);
          accL = __builtin_amdgcn_mfma_f32_32x32x16_bf16(a, bb[ks], accL, 0, 0, 0);
        }
      }
    }
  }
  // coalesced atomic epilogue: col(lane) = n, row = t (ONE per block)
  {
    const int nn = nh + l31;
#pragma unroll
    for (int r = 0; r < 16; ++r) {
      const int t = th + (r & 3) + 8 * (r >> 2) + (g8 >> 1);
      const int tt = cb + t;
      if (t < 60 && tt < T)
        atomicAdd(&lin[((size_t)b * T + tt) * 64 + nn], accL[r]);
    }
  }
}

// ---------------------------------------------------------------------------
// gi GEMM, both branches: grid (191, 3); N=192, K=64.
// ---------------------------------------------------------------------------
__global__ __launch_bounds__(256) void gemm_gi_kernel(
    const float* __restrict__ Ae, const float* __restrict__ Wte,
    const float* __restrict__ biase, float* __restrict__ oute,
    const float* __restrict__ At, const float* __restrict__ Wtt,
    const float* __restrict__ biast, float* __restrict__ outt) {
  const int bx = blockIdx.x;
  const bool ev = bx < 127;
  const float* A = ev ? Ae : At;
  const float* Wt = ev ? Wte : Wtt;
  const float* bias = ev ? biase : biast;
  float* out = ev ? oute : outt;
  const int r0 = (ev ? bx : bx - 127) * 64;
  const int N = 192, K = 64;
  __shared__ float sA[64 * 33];
  __shared__ float sB[64 * 33];
  const int tid = threadIdx.x;
  const int n0 = blockIdx.y * 64;
  const int ty = tid >> 4, tx = tid & 15;
  float acc[4][4] = {};
  for (int kc = 0; kc < K; kc += 32) {
    __syncthreads();
#pragma unroll
    for (int rep = 0; rep < 8; ++rep) {
      const int l = tid + rep * 256;
      const int row = l >> 5, kk = l & 31;
      sA[row * 33 + kk] = A[(size_t)(r0 + row) * K + kc + kk];
      sB[row * 33 + kk] = Wt[(size_t)(n0 + row) * K + kc + kk];
    }
    __syncthreads();
#pragma unroll 8
    for (int kk = 0; kk < 32; ++kk) {
      const float a0 = sA[(ty * 4 + 0) * 33 + kk];
      const float a1 = sA[(ty * 4 + 1) * 33 + kk];
      const float a2 = sA[(ty * 4 + 2) * 33 + kk];
      const float a3 = sA[(ty * 4 + 3) * 33 + kk];
      const float b0 = sB[(tx * 4 + 0) * 33 + kk];
      const float b1 = sB[(tx * 4 + 1) * 33 + kk];
      const float b2 = sB[(tx * 4 + 2) * 33 + kk];
      const float b3 = sB[(tx * 4 + 3) * 33 + kk];
      acc[0][0] = fmaf(a0, b0, acc[0][0]); acc[0][1] = fmaf(a0, b1, acc[0][1]);
      acc[0][2] = fmaf(a0, b2, acc[0][2]); acc[0][3] = fmaf(a0, b3, acc[0][3]);
      acc[1][0] = fmaf(a1, b0, acc[1][0]); acc[1][1] = fmaf(a1, b1, acc[1][1]);
      acc[1][2] = fmaf(a1, b2, acc[1][2]); acc[1][3] = fmaf(a1, b3, acc[1][3]);
      acc[2][0] = fmaf(a2, b0, acc[2][0]); acc[2][1] = fmaf(a2, b1, acc[2][1]);
      acc[2][2] = fmaf(a2, b2, acc[2][2]); acc[2][3] = fmaf(a2, b3, acc[2][3]);
      acc[3][0] = fmaf(a3, b0, acc[3][0]); acc[3][1] = fmaf(a3, b1, acc[3][1]);
      acc[3][2] = fmaf(a3, b2, acc[3][2]); acc[3][3] = fmaf(a3, b3, acc[3][3]);
    }
  }
#pragma unroll
  for (int i = 0; i < 4; ++i)
#pragma unroll
    for (int j = 0; j < 4; ++j)
      out[(size_t)(r0 + ty * 4 + i) * N + n0 + tx * 4 + j] =
          acc[i][j] + bias[n0 + tx * 4 + j];
}

// ---------------------------------------------------------------------------
// GRU, both branches (grid 191). fp32 xy + bf16 xy_bf; logits (eval);
// t^T bf16 scatter (template).
// ---------------------------------------------------------------------------
__global__ __launch_bounds__(256) void gru_rec_kernel(
    float* __restrict__ xyE, const float* __restrict__ giE,
    const float* __restrict__ whhE, const float* __restrict__ bhhE,
    float* __restrict__ xyT, const float* __restrict__ giT,
    const float* __restrict__ whhT, const float* __restrict__ bhhT,
    u16* __restrict__ xybfE, u16* __restrict__ xybfT, u16* __restrict__ ttbf,
    const float* __restrict__ a_w, const float* __restrict__ a_b,
    float* __restrict__ logits) {
  const int bxid = blockIdx.x;
  const bool ev = bxid < 127;
  float* xy = ev ? xyE : xyT;
  u16* xybf = ev ? xybfE : xybfT;
  const float* gi = ev ? giE : giT;
  const float* whh = ev ? whhE : whhT;
  const float* bhh = ev ? bhhE : bhhT;
  const int T = ev ? 2032 : 1024;
  const int t0 = (ev ? bxid : bxid - 127) * 16;
  __shared__ float s_whh_t[64 * 192];
  __shared__ float s_h[16][64];
  __shared__ float s_aw[64];
  const int tid = threadIdx.x;
  const int lane = tid & 63, wave = tid >> 6;
  for (int i = tid; i < 192 * 64; i += 256) {
    const int j = i >> 6, d = i & 63;
    s_whh_t[d * 192 + j] = whh[i];
  }
  for (int i = tid; i < 16 * 64; i += 256) (&s_h[0][0])[i] = 0.f;
  if (tid < 64) s_aw[tid] = a_w[tid];
  const float ab = a_b[0];
  const float bhr = bhh[lane], bhz = bhh[64 + lane], bhn = bhh[128 + lane];
  __syncthreads();
  for (int b = 0; b < 4; ++b) {
    float gir[4], giz[4], gin[4];
#pragma unroll
    for (int sl = 0; sl < 4; ++sl) {
      int t = t0 + wave * 4 + sl; if (t > T - 1) t = T - 1;
      const float* girow = gi + ((size_t)b * T + t) * 192;
      gir[sl] = girow[lane]; giz[sl] = girow[64 + lane]; gin[sl] = girow[128 + lane];
    }
    float ahr[4] = {}, ahz[4] = {}, ahn[4] = {};
    for (int d = 0; d < 64; ++d) {
      const float wr_ = s_whh_t[d * 192 + lane];
      const float wz_ = s_whh_t[d * 192 + 64 + lane];
      const float wn_ = s_whh_t[d * 192 + 128 + lane];
#pragma unroll
      for (int sl = 0; sl < 4; ++sl) {
        const float hv = s_h[wave * 4 + sl][d];
        ahr[sl] = fmaf(wr_, hv, ahr[sl]);
        ahz[sl] = fmaf(wz_, hv, ahz[sl]);
        ahn[sl] = fmaf(wn_, hv, ahn[sl]);
      }
    }
    float hn[4];
#pragma unroll
    for (int sl = 0; sl < 4; ++sl) {
      const float r = 1.f / (1.f + __expf(-(gir[sl] + ahr[sl] + bhr)));
      const float z = 1.f / (1.f + __expf(-(giz[sl] + ahz[sl] + bhz)));
      const float n = tanhf(gin[sl] + r * (ahn[sl] + bhn));
      hn[sl] = (1.f - z) * n + z * s_h[wave * 4 + sl][lane];
    }
    __syncthreads();
#pragma unroll
    for (int sl = 0; sl < 4; ++sl) {
      const int t = t0 + wave * 4 + sl;
      s_h[wave * 4 + sl][lane] = hn[sl];
      if (t < T) {
        const size_t idx = ((size_t)b * T + t) * 64 + lane;
        xy[idx] = hn[sl];
        xybf[idx] = f2bf(hn[sl]);
        if (ev) {
          float v = hn[sl] * s_aw[lane];
#pragma unroll
          for (int off = 32; off > 0; off >>= 1) v += __shfl_down(v, off, 64);
          if (lane == 0) logits[b * 2032 + t] = v + ab;
        } else {
          ttbf[((size_t)b * 64 + lane) * 1024 + t] = f2bf(hn[sl]);
        }
      }
    }
    __syncthreads();
  }
}

// ---------------------------------------------------------------------------
// scores: P'[b,tau,eps] = exp(sum_d t[tau,d] e[eps,d]) + per-tau rowsums.
// |s| <= 64 so exp never overflows. grid (16,16,4).
// ---------------------------------------------------------------------------
__global__ __launch_bounds__(256) void scores_mfma_kernel(
    const u16* __restrict__ tbf, const u16* __restrict__ ebf,
    u16* __restrict__ P, float* __restrict__ rowsum) {
  __shared__ __align__(16) u16 sA[64 * 72];
  __shared__ __align__(16) u16 sB[128 * 72];
  const int tid = threadIdx.x;
  const int b = blockIdx.z;
  const int tau0 = blockIdx.x * 64;
  const int e0 = blockIdx.y * 128;
  const int lane = tid & 63, wave = tid >> 6;
  const int l31 = lane & 31, g8 = (lane >> 5) * 8;
  {
    const int row = tid >> 2, seg = (tid & 3) * 16;
    const u16* ap = &tbf[((size_t)b * 1024 + tau0 + row) * 64 + seg];
    u16* da = &sA[row * 72 + seg];
    *(u16x8*)da = *(const u16x8*)ap;
    *(u16x8*)(da + 8) = *(const u16x8*)(ap + 8);
  }
#pragma unroll
  for (int r = 0; r < 4; ++r) {
    const int q = tid + r * 256;
    const int row = q >> 3, seg = (q & 7) * 8;
    int eps = e0 + row; if (eps > 2031) eps = 2031;
    *(u16x8*)&sB[row * 72 + seg] =
        *(const u16x8*)&ebf[((size_t)b * 2032 + eps) * 64 + seg];
  }
  __syncthreads();
  const int mh = (wave & 1) * 32;
  const int nq = (wave >> 1) * 64;
  f32x16 acc0 = {}, acc1 = {};
#pragma unroll
  for (int ks = 0; ks < 4; ++ks) {
    bf16x8 a = *(const bf16x8*)&sA[(mh + l31) * 72 + ks * 16 + g8];
    bf16x8 b0 = *(const bf16x8*)&sB[(nq + l31) * 72 + ks * 16 + g8];
    bf16x8 b1 = *(const bf16x8*)&sB[(nq + 32 + l31) * 72 + ks * 16 + g8];
    acc0 = __builtin_amdgcn_mfma_f32_32x32x16_bf16(a, b0, acc0, 0, 0, 0);
    acc1 = __builtin_amdgcn_mfma_f32_32x32x16_bf16(a, b1, acc1, 0, 0, 0);
  }
  const int ep0 = e0 + nq + l31;
  const int ep1 = ep0 + 32;
#pragma unroll
  for (int r = 0; r < 16; ++r) {
    const int tau = tau0 + mh + (r & 3) + 8 * (r >> 2) + (g8 >> 1);
    const size_t prow = ((size_t)b * 1024 + tau) * 2032;
    const float e0v = __expf(acc0[r]);
    const float e1v = __expf(acc1[r]);
    float part = 0.f;
    if (ep0 < 2032) { P[prow + ep0] = f2bf(e0v); part += e0v; }
    if (ep1 < 2032) { P[prow + ep1] = f2bf(e1v); part += e1v; }
#pragma unroll
    for (int off = 16; off > 0; off >>= 1) part += __shfl_down(part, off, 32);
    if (l31 == 0) atomicAdd(&rowsum[b * 1024 + tau], part);
  }
}

// ---------------------------------------------------------------------------
// pv on bf16 MFMA with folded softmax normalization (1/rowsum applied in
// the P^T LDS transpose). grid (32, 4, 4); atomic f32 epilogue.
// ---------------------------------------------------------------------------
__global__ __launch_bounds__(256) void pv_mfma_kernel(
    const u16* __restrict__ P, const u16* __restrict__ ttbf,
    const float* __restrict__ rowsum, float* __restrict__ PV) {
  __shared__ __align__(16) u16 sPT[64 * 72];  // [eps][tau], pre-normalized
  __shared__ __align__(16) u16 sTT[64 * 72];  // [d][tau]
  const int tid = threadIdx.x;
  const int b = blockIdx.z;
  const int e0 = blockIdx.x * 64;
  const int tau_base = blockIdx.y * 256;
  const int lane = tid & 63, wave = tid >> 6;
  const int l31 = lane & 31, g8 = (lane >> 5) * 8;
  const int mh = (wave & 1) * 32, nh = (wave >> 1) * 32;
  f32x16 acc = {};
  for (int cc = 0; cc < 4; ++cc) {
    const int tc = tau_base + cc * 64;
    __syncthreads();
#pragma unroll
    for (int k = 0; k < 2; ++k) {
      const int q = tid + k * 256;
      const int row = q >> 3, seg = (q & 7) * 8;
      const float inv = 1.0f / rowsum[b * 1024 + tc + row];
      int er = e0 + seg;
      if (er > 2032 - 8) er = 2032 - 8;
      const u16x8 v = *(const u16x8*)&P[((size_t)b * 1024 + tc + row) * 2032 + er];
#pragma unroll
      for (int j = 0; j < 8; ++j)
        sPT[(seg + j) * 72 + row] = f2bf(bf2f(v[j]) * inv);
    }
#pragma unroll
    for (int k = 0; k < 2; ++k) {
      const int q = tid + k * 256;
      const int row = q >> 3, seg = (q & 7) * 8;
      *(u16x8*)&sTT[row * 72 + seg] =
          *(const u16x8*)&ttbf[((size_t)b * 64 + row) * 1024 + tc + seg];
    }
    __syncthreads();
#pragma unroll
    for (int ks = 0; ks < 4; ++ks) {
      bf16x8 a = *(const bf16x8*)&sPT[(mh + l31) * 72 + ks * 16 + g8];
      bf16x8 bb = *(const bf16x8*)&sTT[(nh + l31) * 72 + ks * 16 + g8];
      acc = __builtin_amdgcn_mfma_f32_32x32x16_bf16(a, bb, acc, 0, 0, 0);
    }
  }
#pragma unroll
  for (int r = 0; r < 16; ++r) {
    const int eps = e0 + mh + (r & 3) + 8 * (r >> 2) + (g8 >> 1);
    if (eps < 2032)
      atomicAdd(&PV[((size_t)b * 2032 + eps) * 64 + nh + l31], acc[r]);
  }
}

// ---------------------------------------------------------------------------
// red_reduce with fused att softmax (per-block redundant softmax of logits).
// grid (16, 4).
// ---------------------------------------------------------------------------
__global__ __launch_bounds__(256) void red_reduce_kernel(
    const float* __restrict__ emat, const float* __restrict__ PV,
    const float* __restrict__ logits, float* __restrict__ red) {
  __shared__ float s_att[2032];
  __shared__ float sred[4];
  __shared__ float s_part[4][64];
  const int tid = threadIdx.x;
  const int lane = tid & 63, wave = tid >> 6;
  const int b = blockIdx.y;
  float m = -3.4e38f;
  for (int i = tid; i < 2032; i += 256) {
    const float v = logits[b * 2032 + i];
    s_att[i] = v;
    m = fmaxf(m, v);
  }
#pragma unroll
  for (int off = 32; off > 0; off >>= 1) m = fmaxf(m, __shfl_down(m, off, 64));
  if (lane == 0) sred[wave] = m;
  __syncthreads();
  m = fmaxf(fmaxf(sred[0], sred[1]), fmaxf(sred[2], sred[3]));
  __syncthreads();
  float ssum = 0.f;
  for (int i = tid; i < 2032; i += 256) {
    const float v = __expf(s_att[i] - m);
    s_att[i] = v;
    ssum += v;
  }
#pragma unroll
  for (int off = 32; off > 0; off >>= 1) ssum += __shfl_down(ssum, off, 64);
  if (lane == 0) sred[wave] = ssum;
  __syncthreads();
  const float inv = 1.f / (sred[0] + sred[1] + sred[2] + sred[3]);
  const int i0 = blockIdx.x * 127;
  float acc = 0.f;
  for (int i = i0 + wave; i < i0 + 127; i += 4) {
    const size_t idx = ((size_t)b * 2032 + i) * 64 + lane;
    acc = fmaf(fabsf(PV[idx] - emat[idx]), s_att[i], acc);
  }
  s_part[wave][lane] = acc;
  __syncthreads();
  if (tid < 64)
    atomicAdd(&red[b * 64 + tid],
              (s_part[0][tid] + s_part[1][tid] + s_part[2][tid] + s_part[3][tid]) * inv);
}

// ---------------------------------------------------------------------------
// mlp: h = relu(red@h_w^T + h_b); out = softmax(h@c_w^T + c_b). grid 4.
// ---------------------------------------------------------------------------
__global__ __launch_bounds__(128) void mlp_kernel(
    const float* __restrict__ red, const float* __restrict__ h_w,
    const float* __restrict__ h_b, const float* __restrict__ c_w,
    const float* __restrict__ c_b, float* __restrict__ out) {
  __shared__ float s_red[64];
  __shared__ float s_hv[128];
  const int tid = threadIdx.x;
  const int b = blockIdx.x;
  if (tid < 64) s_red[tid] = red[b * 64 + tid];
  __syncthreads();
  {
    float acc = h_b[tid];
    const float* hw = h_w + tid * 64;
    for (int d = 0; d < 64; ++d) acc = fmaf(s_red[d], hw[d], acc);
    s_hv[tid] = fmaxf(acc, 0.f);
  }
  __syncthreads();
  if (tid == 0) {
    float l0 = c_b[0], l1 = c_b[1];
    for (int j = 0; j < 128; ++j) {
      l0 = fmaf(s_hv[j], c_w[j], l0);
      l1 = fmaf(s_hv[j], c_w[128 + j], l1);
    }
    const float mm = fmaxf(l0, l1);
    const float e0 = __expf(l0 - mm), e1 = __expf(l1 - mm);
    const float invs = 1.f / (e0 + e1);
    out[b * 2 + 0] = e0 * invs;
    out[b * 2 + 1] = e1 * invs;
  }
}

// ===========================================================================
extern "C" void kernel_launch(void* const* d_in, const int* in_sizes, int n_in,
                              void* d_out, int out_size, void* d_ws, size_t ws_size,
                              hipStream_t stream) {
  const float* evaluation = (const float*)d_in[0];
  const float* templ      = (const float*)d_in[1];
  const float* e_w1 = (const float*)d_in[2];
  const float* e_b1 = (const float*)d_in[3];
  const float* e_w2 = (const float*)d_in[4];
  const float* e_b2 = (const float*)d_in[5];
  const float* e_w3 = (const float*)d_in[6];
  const float* e_b3 = (const float*)d_in[7];
  const float* el_w = (const float*)d_in[8];
  const float* el_b = (const float*)d_in[9];
  const float* eg_wih = (const float*)d_in[10];
  const float* eg_whh = (const float*)d_in[11];
  const float* eg_bih = (const float*)d_in[12];
  const float* eg_bhh = (const float*)d_in[13];
  const float* t_w1 = (const float*)d_in[14];
  const float* t_b1 = (const float*)d_in[15];
  const float* t_w2 = (const float*)d_in[16];
  const float* t_b2 = (const float*)d_in[17];
  const float* t_w3 = (const float*)d_in[18];
  const float* t_b3 = (const float*)d_in[19];
  const float* tl_w = (const float*)d_in[20];
  const float* tl_b = (const float*)d_in[21];
  const float* tg_wih = (const float*)d_in[22];
  const float* tg_whh = (const float*)d_in[23];
  const float* tg_bih = (const float*)d_in[24];
  const float* tg_bhh = (const float*)d_in[25];
  const float* a_w = (const float*)d_in[26];
  const float* a_b = (const float*)d_in[27];
  const float* h_w = (const float*)d_in[28];
  const float* h_b = (const float*)d_in[29];
  const float* c_w = (const float*)d_in[30];
  const float* c_b = (const float*)d_in[31];

  float* ws = (float*)d_ws;
  float* beff_e  = ws + OFF_BEFF_E;
  float* beff_t  = ws + OFF_BEFF_T;
  float* bias2_e = ws + OFF_BIAS2_E;
  float* bias2_t = ws + OFF_BIAS2_T;
  u16*   wkx_e   = (u16*)(ws + OFF_WKX_E);
  u16*   wkx_t   = (u16*)(ws + OFF_WKX_T);
  float* w12p_e  = ws + OFF_W12P_E;
  float* w12p_t  = ws + OFF_W12P_T;
  float* b12_e   = ws + OFF_B12_E;
  float* b12_t   = ws + OFF_B12_T;
  u16*   lwt1_e  = (u16*)(ws + OFF_LWT1_E);
  u16*   lwt1_t  = (u16*)(ws + OFF_LWT1_T);
  float* attbuf  = ws + OFF_ATT;
  u16*   xybf_e  = (u16*)(ws + OFF_XYBF_E);
  u16*   xybf_t  = (u16*)(ws + OFF_XYBF_T);
  u16*   ttbf    = (u16*)(ws + OFF_TTBF);
  float* lin_e   = ws + OFF_LIN_E;
  float* lin_t   = ws + OFF_LIN_T;
  float* PVbuf   = ws + OFF_PV;
  float* redbuf  = ws + OFF_RED;
  float* rsum    = ws + OFF_RSUM;
  float* gi_e    = ws + OFF_GI_E;
  float* gi_t    = ws + OFF_GI_T;
  u16*   Pbuf    = (u16*)(ws + OFF_P);

  // prep (zeroes lin/PV/red/rowsum + compose12 + gi_bias + lw->lwT1), weff
  prep_kernel<<<530, 320, 0, stream>>>(
      e_w1, e_b1, e_w2, e_b2, t_w1, t_b1, t_w2, t_b2, w12p_e, w12p_t, b12_e, b12_t,
      eg_wih, eg_bih, el_b, bias2_e, tg_wih, tg_bih, tl_b, bias2_t,
      el_w, tl_w, lwt1_e, lwt1_t, (float4*)lin_e);
  compose_weff_kernel<<<dim3(64, 2), 256, 0, stream>>>(
      e_w3, e_b3, t_w3, t_b3, w12p_e, w12p_t, b12_e, b12_t, wkx_e, wkx_t, beff_e, beff_t);

  // fused conv+pool+linear (by-loop in-block, atomic into lin), then GRU chain
  conv_pool_lin_kernel<<<dim3(34, 10, 8), 256, 0, stream>>>(
      evaluation, wkx_e, beff_e, lwt1_e, lin_e,
      templ, wkx_t, beff_t, lwt1_t, lin_t);
  gemm_gi_kernel<<<dim3(191, 3), 256, 0, stream>>>(
      lin_e, eg_wih, bias2_e, gi_e, lin_t, tg_wih, bias2_t, gi_t);
  gru_rec_kernel<<<191, 256, 0, stream>>>(
      lin_e, gi_e, eg_whh, eg_bhh, lin_t, gi_t, tg_whh, tg_bhh,
      xybf_e, xybf_t, ttbf, a_w, a_b, attbuf);

  // cross attention: exp-scores (+rowsum) -> normalized pv (softmax folded)
  scores_mfma_kernel<<<dim3(16, 16, 4), 256, 0, stream>>>(xybf_t, xybf_e, Pbuf, rsum);
  pv_mfma_kernel<<<dim3(32, 4, 4), 256, 0, stream>>>(Pbuf, ttbf, rsum, PVbuf);

  // head: (att softmax fused into) weighted reduce -> MLP
  red_reduce_kernel<<<dim3(16, 4), 256, 0, stream>>>(lin_e, PVbuf, attbuf, redbuf);
  mlp_kernel<<<4, 128, 0, stream>>>(redbuf, h_w, h_b, c_w, c_b, (float*)d_out);
}

// Round 8
// 304.905 us; speedup vs baseline: 1.2677x; 1.0032x over previous
//
#include <hip/hip_runtime.h>
#include <hip/hip_bf16.h>
#include <cmath>

// ============================================================================
// DeepTemplateMatchingModule on MI355X — round 20 (resubmit; prior run was an
// infra failure: "container failed twice", no test/counter output).
// R19 closed the conv investigation: 5 structurally independent variants all
// land 98-104us with clean traffic -> decomposition floor; keep R19's conv.
// R20 pivots to the attention chain, which carries pure waste: P (16.6MB)
// written+read, PV 4-way atomic RMW, red_reduce re-reads PV+emat — while
// QK^T is only ~1GFLOP (trivial to recompute) and PV's sole consumer is red.
// New chain: rowsum (scores minus P stores) -> att_softmax (tiny) ->
// pv_red: per (b, 64-eps) block sweeps all tau, recomputes QK+exp,
// normalizes with preloaded 1/rs, LDS-transposes, MFMA-accumulates PV in
// REGISTERS, and folds |PV-e|*att into red in the epilogue. PV never hits
// memory; P buffer deleted; PV zeroing deleted; red_reduce deleted.
// ============================================================================

typedef unsigned short u16;
typedef unsigned int u32;
typedef __attribute__((ext_vector_type(8))) short bf16x8;
typedef __attribute__((ext_vector_type(8))) unsigned short u16x8;
typedef __attribute__((ext_vector_type(16))) float f32x16;

__device__ __forceinline__ u16 f2bf(float f) {
  unsigned int x = __float_as_uint(f);
  return (u16)((x + 0x7fffu + ((x >> 16) & 1u)) >> 16);
}
__device__ __forceinline__ float bf2f(u16 v) {
  return __uint_as_float(((unsigned int)v) << 16);
}
__device__ __forceinline__ u32 f2bf_pk(float a, float b) {
  __hip_bfloat162 h = __float22bfloat162_rn(float2{a, b});
  u32 r;
  __builtin_memcpy(&r, &h, 4);  // low 16 = a, high 16 = b
  return r;
}

// ---- workspace layout (float offsets) ----
static const size_t OFF_BEFF_E  = 0;          // 64
static const size_t OFF_BEFF_T  = 64;
static const size_t OFF_BIAS2_E = 128;        // 192
static const size_t OFF_BIAS2_T = 320;
static const size_t OFF_WKX_E   = 512;        // 4 parities x 13x64x16 u16 = 26624 f
static const size_t OFF_WKX_T   = 27136;      // 26624 f
static const size_t OFF_W12P_E  = 53760;      // 9248
static const size_t OFF_W12P_T  = 63008;      // 9248
static const size_t OFF_B12_E   = 72256;      // 32
static const size_t OFF_B12_T   = 72288;      // 32
static const size_t OFF_LWT1_E  = 72320;      // lwT1[h][n][c] bf16: 237568 u16 = 118784 f
static const size_t OFF_LWT1_T  = 191104;     // 118784 f
static const size_t OFF_ATT     = 309888;     // 8128 f (raw logits)
static const size_t OFF_XYBF_E  = 318016;     // 260096 f (4x2032x64 u16)
static const size_t OFF_XYBF_T  = 578112;     // 131072 f (4x1024x64 u16)
static const size_t OFF_TTBF    = 709184;     // 131072 f (t^T: 4x64x1024 u16)
// contiguous zero region (zeroed by prep): lin_e, lin_t, red, rowsum
static const size_t OFF_LIN_E   = 840256;     // 520192 f
static const size_t OFF_LIN_T   = 1360448;    // 262144 f
static const size_t OFF_RED     = 1622592;    // 256 f
static const size_t OFF_RSUM    = 1622848;    // 4096 f
static const size_t ZERO_F4     = 196672;     // 786,688 f / 4
static const size_t ZSTRIDE     = 372;        // 530 * 372 >= 196672
static const size_t OFF_ATTW    = 1626944;    // 8128 f (softmaxed att weights)
static const size_t OFF_GI_E    = 2147136;    // 1,560,576 f
static const size_t OFF_GI_T    = 3707712;    // 786,432 f

// ---------------------------------------------------------------------------
// prep: zero region + compose12 (bx<64) + gi_bias (64..65) + lw->lwT1 (>=66).
// lwT1[h][n][c] = bf16(lw[n][c*58+h]); 237,568 els per branch.
// ---------------------------------------------------------------------------
__global__ __launch_bounds__(320) void prep_kernel(
    const float* __restrict__ w1e, const float* __restrict__ b1e,
    const float* __restrict__ w2e, const float* __restrict__ b2e,
    const float* __restrict__ w1t, const float* __restrict__ b1t,
    const float* __restrict__ w2t, const float* __restrict__ b2t,
    float* __restrict__ w12p_e, float* __restrict__ w12p_t,
    float* __restrict__ b12o_e, float* __restrict__ b12o_t,
    const float* __restrict__ wih_e, const float* __restrict__ bih_e,
    const float* __restrict__ lb_e, float* __restrict__ bias2_e,
    const float* __restrict__ wih_t, const float* __restrict__ bih_t,
    const float* __restrict__ lb_t, float* __restrict__ bias2_t,
    const float* __restrict__ lwe, const float* __restrict__ lwt,
    u16* __restrict__ lwt1_e, u16* __restrict__ lwt1_t,
    float4* __restrict__ zbase) {
  const int bx = blockIdx.x;
  const int tid = threadIdx.x;
  {
    const size_t base = (size_t)bx * ZSTRIDE;
    const float4 z = {0.f, 0.f, 0.f, 0.f};
    for (size_t i = base + tid; i < base + ZSTRIDE && i < ZERO_F4; i += 320)
      zbase[i] = z;
  }
  if (bx >= 66) {  // lw -> lwT1 (transpose + bf16)
    if (tid < 256) {
      const int k = bx - 66;
      const int br = k / 232, j = k - br * 232;
      const float* src = br ? lwt : lwe;
      u16* dst = br ? lwt1_t : lwt1_e;
      const int e = j * 1024 + tid * 4;   // 232*1024 = 237,568
      const int h = e >> 12;              // /4096
      const int rem = e & 4095;
      const int n = rem >> 6, c = rem & 63;
      const float* s = src + (size_t)n * 3712 + (size_t)c * 58 + h;
      const float v0 = s[0], v1 = s[58], v2 = s[116], v3 = s[174];
      *(u32*)&dst[e] = f2bf_pk(v0, v1);
      *(u32*)&dst[e + 2] = f2bf_pk(v2, v3);
    }
    return;
  }
  if (bx >= 64) {  // gi_bias
    const int br = bx - 64;
    const float* wih = br ? wih_t : wih_e;
    const float* bih = br ? bih_t : bih_e;
    const float* lb = br ? lb_t : lb_e;
    float* bias2 = br ? bias2_t : bias2_e;
    __shared__ float s_lb[64];
    if (tid < 64) s_lb[tid] = lb[tid];
    __syncthreads();
    if (tid < 192) {
      float acc = bih[tid];
      const float* wr = wih + tid * 64;
      for (int d = 0; d < 64; ++d) acc = fmaf(wr[d], s_lb[d], acc);
      bias2[tid] = acc;
    }
    return;
  }
  // compose12
  const int br = bx >> 5;
  const float* w1 = br ? w1t : w1e;
  const float* b1 = br ? b1t : b1e;
  const float* w2 = br ? w2t : w2e;
  const float* b2 = br ? b2t : b2e;
  float* w12p = br ? w12p_t : w12p_e;
  float* b12o = br ? b12o_t : b12o_e;
  const int c12 = bx & 31;
  __shared__ float s_w1pad[16 * 169];
  __shared__ float s_w2c[400];
  __shared__ float s_b1[16];
  for (int i = tid; i < 2704; i += 320) s_w1pad[i] = 0.f;
  if (tid < 16) s_b1[tid] = b1[tid];
  __syncthreads();
  for (int i = tid; i < 400; i += 320) {
    const int c1 = i / 25, r = (i % 25) / 5, cc = i % 5;
    s_w1pad[c1 * 169 + (r + 4) * 13 + (cc + 4)] = w1[i];
    s_w2c[i] = w2[c12 * 400 + i];
  }
  __syncthreads();
  if (tid < 289) {
    const int py = tid / 17, px = tid % 17;
    float v = 0.f;
    if (py >= 4 && py <= 12 && px >= 4 && px <= 12) {
      const int sy = py - 4, sx = px - 4;
      float accs[2] = {0.f, 0.f};
      for (int c1 = 0; c1 < 16; ++c1) {
        const float* w2p = s_w2c + c1 * 25;
        const float* w1p = s_w1pad + c1 * 169 + (sy + 4) * 13 + (sx + 4);
#pragma unroll
        for (int uy = 0; uy < 5; ++uy)
#pragma unroll
          for (int ux = 0; ux < 5; ++ux)
            accs[uy & 1] = fmaf(w2p[uy * 5 + ux], w1p[-(uy * 13) - ux], accs[uy & 1]);
      }
      v = accs[0] + accs[1];
    }
    w12p[c12 * 289 + tid] = v;
  } else if (tid == 300) {
    float acc = b2[c12];
    for (int c1 = 0; c1 < 16; ++c1) {
      float sw = 0.f;
      for (int u = 0; u < 25; ++u) sw += s_w2c[c1 * 25 + u];
      acc = fmaf(sw, s_b1[c1], acc);
    }
    b12o[c12] = acc;
  }
}

// ---------------------------------------------------------------------------
// compose_weff: 4 parity layouts wkx[(p*13+kx)*64+o][16] bf16 (slot ky+p).
// ---------------------------------------------------------------------------
__global__ __launch_bounds__(256) void compose_weff_kernel(
    const float* __restrict__ w3e, const float* __restrict__ b3e,
    const float* __restrict__ w3t, const float* __restrict__ b3t,
    const float* __restrict__ w12p_e, const float* __restrict__ w12p_t,
    const float* __restrict__ b12_e, const float* __restrict__ b12_t,
    u16* __restrict__ wkx_e, u16* __restrict__ wkx_t,
    float* __restrict__ beff_e, float* __restrict__ beff_t) {
  const int br = blockIdx.y;
  const float* w3 = br ? w3t : w3e;
  const float* b3 = br ? b3t : b3e;
  const float* w12p = br ? w12p_t : w12p_e;
  const float* b12 = br ? b12_t : b12_e;
  u16* wkx = br ? wkx_t : wkx_e;
  float* beff = br ? beff_t : beff_e;
  const int o = blockIdx.x;
  __shared__ float s_pad[32 * 289];
  __shared__ float s_w3o[800];
  __shared__ float s_b12[32];
  const int tid = threadIdx.x;
  for (int i = tid; i < 9248; i += 256) s_pad[i] = w12p[i];
  for (int i = tid; i < 800; i += 256) s_w3o[i] = w3[o * 800 + i];
  if (tid < 32) s_b12[tid] = b12[tid];
  __syncthreads();
  if (tid < 169) {
    const int sy = tid / 13, sx = tid % 13;
    float accs[4] = {0.f, 0.f, 0.f, 0.f};
#pragma unroll 4
    for (int c = 0; c < 32; ++c) {
      const float* w3p = s_w3o + c * 25;
      const float* wp = s_pad + c * 289 + (sy + 4) * 17 + (sx + 4);
#pragma unroll
      for (int uy = 0; uy < 5; ++uy)
#pragma unroll
        for (int ux = 0; ux < 5; ++ux)
          accs[c & 3] = fmaf(w3p[uy * 5 + ux], wp[-(uy * 17) - ux], accs[c & 3]);
    }
    const u16 v = f2bf(accs[0] + accs[1] + accs[2] + accs[3]);
#pragma unroll
    for (int p = 0; p < 4; ++p)
      wkx[((p * 13 + sx) * 64 + o) * 16 + sy + p] = v;
  } else if (tid < 169 + 156) {  // 13 kx x 12 zero-slots
    const int t = tid - 169, kx = t / 12, q = t % 12;
    const int p = q / 3, idx = q % 3;
    const int slot = (idx < p) ? idx : (p + 13) + (idx - p);
    wkx[((p * 13 + kx) * 64 + o) * 16 + slot] = 0;
  }
  if (tid == 255) {
    float acc = b3[o];
    for (int c = 0; c < 32; ++c) {
      float sw = 0.f;
      for (int u = 0; u < 25; ++u) sw += s_w3o[c * 25 + u];
      acc = fmaf(sw, s_b12[c], acc);
    }
    beff[o] = acc;
  }
}

// ---------------------------------------------------------------------------
// FUSED conv13x13 + maxpool + linear (R19 structure, kept: decomposition
// floor ~99us). Per iter: commit prefetched x regs to s_x -> issue next
// tile's loads -> BAR -> per hh: wfrag[13]+bb[4] preload, conv 4 indep
// chains, s_out (stride 72), pool 6x b128, linear 8 MFMA into accL.
// ONE atomic epilogue/block. grid (34, 10, 8).
// ---------------------------------------------------------------------------
__global__ __launch_bounds__(256, 2) void conv_pool_lin_kernel(
    const float* __restrict__ xe, const u16* __restrict__ wkx_e,
    const float* __restrict__ beff_e, const u16* __restrict__ lwt1_e,
    float* __restrict__ lin_e,
    const float* __restrict__ xt, const u16* __restrict__ wkx_t,
    const float* __restrict__ beff_t, const u16* __restrict__ lwt1_t,
    float* __restrict__ lin_t) {
  const int zz = blockIdx.z;
  const bool ev = zz < 4;
  const int b = ev ? zz : zz - 4;
  const int W = ev ? 2048 : 1040;
  const int T = ev ? 2032 : 1024;
  const int cb = blockIdx.x * 60;
  if (cb >= T) return;
  const float* x = ev ? xe : xt;
  const u16* wkx = ev ? wkx_e : wkx_t;
  const float* beff = ev ? beff_e : beff_t;
  const u16* lwt1 = ev ? lwt1_e : lwt1_t;
  float* lin = ev ? lin_e : lin_t;

  __shared__ __align__(16) u16 s_x[80 * 24];       // 3840 B
  __shared__ __align__(16) u16 s_out[2 * 64 * 72]; // 18432 B (stride 72: 16B rows)
  __shared__ __align__(16) u16 s_poolT[64 * 72];   // 9216 B ([t][c])
  __shared__ float s_beff[64];

  const int tid = threadIdx.x;
  const int lane = tid & 63, wave = tid >> 6;
  const int rsel = wave & 1, cm = (wave >> 1) * 32;
  const int l31 = lane & 31, g8 = (lane >> 5) * 8;
  const int th = (wave & 1) * 32, nh = (wave >> 1) * 32;

  if (tid < 64) s_beff[tid] = beff[tid];  // consumed after later barriers

  const int by0 = blockIdx.y * 3;
  const int by1 = (by0 + 3 < 29) ? (by0 + 3) : 29;

  // T14 register prefetch of the x staging rows (chunks i = tid + k*256)
  float p0[3], p1[3];
  {
    const float* xb = x + ((size_t)b * 128 + 4 * by0) * W;
#pragma unroll
    for (int k = 0; k < 3; ++k) {
      const int i = tid + k * 256;
      if (i < 640) {
        const int pr = i / 80, c = i - pr * 80;
        int gc = cb + c;
        if (gc > W - 1) gc = W - 1;
        p0[k] = xb[(size_t)(2 * pr) * W + gc];
        p1[k] = xb[(size_t)(2 * pr + 1) * W + gc];
      }
    }
  }

  f32x16 accL = {};
  for (int by = by0; by < by1; ++by) {
    // commit prefetched x to LDS (safe: prior-iter conv reads of s_x
    // completed before that iter's s_out barrier).
#pragma unroll
    for (int k = 0; k < 3; ++k) {
      const int i = tid + k * 256;
      if (i < 640) {
        const int pr = i / 80, c = i - pr * 80;
        *(u32*)&s_x[c * 24 + 2 * pr] = f2bf_pk(p0[k], p1[k]);
      }
    }
    if (by + 1 < by1) {  // issue next tile's loads; overlap conv/pool/linear
      const float* xb = x + ((size_t)b * 128 + 4 * (by + 1)) * W;
#pragma unroll
      for (int k = 0; k < 3; ++k) {
        const int i = tid + k * 256;
        if (i < 640) {
          const int pr = i / 80, c = i - pr * 80;
          int gc = cb + c;
          if (gc > W - 1) gc = W - 1;
          p0[k] = xb[(size_t)(2 * pr) * W + gc];
          p1[k] = xb[(size_t)(2 * pr + 1) * W + gc];
        }
      }
    }
    __syncthreads();
#pragma unroll
    for (int hh = 0; hh < 2; ++hh) {
      const int p = 2 * hh + rsel;
      const int h = 2 * by + hh;
      bf16x8 wfrag[13];
      {
        const u16* aw = wkx + ((p * 13) * 64 + cm + l31) * 16 + g8;
#pragma unroll
        for (int kx = 0; kx < 13; ++kx) wfrag[kx] = *(const bf16x8*)(aw + kx * 1024);
      }
      bf16x8 bb[4];
      {
        const u16* bp2 = lwt1 + ((size_t)(h * 64 + nh + l31)) * 64 + g8;
#pragma unroll
        for (int ks = 0; ks < 4; ++ks) bb[ks] = *(const bf16x8*)(bp2 + ks * 16);
      }
      // conv: 4 independent accumulate chains, interleaved issue.
      f32x16 c0a = {}, c1a = {}, c0b = {}, c1b = {};
      const u16* bxp = s_x + g8;
#pragma unroll
      for (int kx = 0; kx < 6; ++kx) {
        bf16x8 b0 = *(const bf16x8*)(bxp + (l31 + kx) * 24);
        bf16x8 b1 = *(const bf16x8*)(bxp + (32 + l31 + kx) * 24);
        bf16x8 b0q = *(const bf16x8*)(bxp + (l31 + kx + 7) * 24);
        bf16x8 b1q = *(const bf16x8*)(bxp + (32 + l31 + kx + 7) * 24);
        c0a = __builtin_amdgcn_mfma_f32_32x32x16_bf16(wfrag[kx], b0, c0a, 0, 0, 0);
        c1a = __builtin_amdgcn_mfma_f32_32x32x16_bf16(wfrag[kx], b1, c1a, 0, 0, 0);
        c0b = __builtin_amdgcn_mfma_f32_32x32x16_bf16(wfrag[kx + 7], b0q, c0b, 0, 0, 0);
        c1b = __builtin_amdgcn_mfma_f32_32x32x16_bf16(wfrag[kx + 7], b1q, c1b, 0, 0, 0);
      }
      {  // kx = 6: a-chains only
        bf16x8 b0 = *(const bf16x8*)(bxp + (l31 + 6) * 24);
        bf16x8 b1 = *(const bf16x8*)(bxp + (32 + l31 + 6) * 24);
        c0a = __builtin_amdgcn_mfma_f32_32x32x16_bf16(wfrag[6], b0, c0a, 0, 0, 0);
        c1a = __builtin_amdgcn_mfma_f32_32x32x16_bf16(wfrag[6], b1, c1a, 0, 0, 0);
      }
#pragma unroll
      for (int r = 0; r < 16; ++r) {
        const int c = cm + (r & 3) + 8 * (r >> 2) + (g8 >> 1);
        u16* o = s_out + (rsel * 64 + c) * 72;
        const u32 pk = f2bf_pk(c0a[r] + c0b[r], c1a[r] + c1b[r]);
        o[l31] = (u16)pk;
        o[32 + l31] = (u16)(pk >> 16);
      }
      __syncthreads();  // s_out complete; prior GEMM reads of s_poolT done
      {
        const int pc = tid & 63, tg = tid >> 6;
        const int t0 = tg * 16;  // 0,16,32,48; outputs t0..min(t0+15,59)
        const float bias = s_beff[pc];
        const u16* r0p = s_out + pc * 72 + t0;
        const u16* r1p = s_out + (64 + pc) * 72 + t0;
        const u16x8 a0 = *(const u16x8*)(r0p);
        const u16x8 a1 = *(const u16x8*)(r0p + 8);
        const u16x8 a2 = *(const u16x8*)(r0p + 16);
        const u16x8 q0 = *(const u16x8*)(r1p);
        const u16x8 q1 = *(const u16x8*)(r1p + 8);
        const u16x8 q2 = *(const u16x8*)(r1p + 16);
        float m01[20];
#pragma unroll
        for (int j = 0; j < 8; ++j) {
          m01[j] = fmaxf(bf2f(a0[j]), bf2f(q0[j]));
          m01[j + 8] = fmaxf(bf2f(a1[j]), bf2f(q1[j]));
          if (j < 4) m01[j + 16] = fmaxf(bf2f(a2[j]), bf2f(q2[j]));
        }
#pragma unroll
        for (int i = 0; i < 16; ++i) {
          if (t0 + i < 60) {  // wave-uniform tail guard (tg==3 -> 12 outputs)
            float m = m01[i];
#pragma unroll
            for (int k = 1; k < 5; ++k) m = fmaxf(m, m01[i + k]);
            s_poolT[(t0 + i) * 72 + pc] = f2bf(m + bias);  // transposed (+bias)
          }
        }
      }
      __syncthreads();  // s_poolT complete
      // linear: accL[t][n] += sum_c poolT[t][c] * lwT1[h][n][c] (bb prefetched)
      {
        const u16* ap2 = s_poolT + (th + l31) * 72 + g8;
#pragma unroll
        for (int ks = 0; ks < 4; ++ks) {
          bf16x8 a = *(const bf16x8*)(ap2 + ks * 16);
          accL = __builtin_amdgcn_mfma_f32_32x32x16_bf16(a, bb[ks], accL, 0, 0, 0);
        }
      }
    }
  }
  // coalesced atomic epilogue: col(lane) = n, row = t (ONE per block)
  {
    const int nn = nh + l31;
#pragma unroll
    for (int r = 0; r < 16; ++r) {
      const int t = th + (r & 3) + 8 * (r >> 2) + (g8 >> 1);
      const int tt = cb + t;
      if (t < 60 && tt < T)
        atomicAdd(&lin[((size_t)b * T + tt) * 64 + nn], accL[r]);
    }
  }
}

// ---------------------------------------------------------------------------
// gi GEMM, both branches: grid (191, 3); N=192, K=64.
// ---------------------------------------------------------------------------
__global__ __launch_bounds__(256) void gemm_gi_kernel(
    const float* __restrict__ Ae, const float* __restrict__ Wte,
    const float* __restrict__ biase, float* __restrict__ oute,
    const float* __restrict__ At, const float* __restrict__ Wtt,
    const float* __restrict__ biast, float* __restrict__ outt) {
  const int bx = blockIdx.x;
  const bool ev = bx < 127;
  const float* A = ev ? Ae : At;
  const float* Wt = ev ? Wte : Wtt;
  const float* bias = ev ? biase : biast;
  float* out = ev ? oute : outt;
  const int r0 = (ev ? bx : bx - 127) * 64;
  const int N = 192, K = 64;
  __shared__ float sA[64 * 33];
  __shared__ float sB[64 * 33];
  const int tid = threadIdx.x;
  const int n0 = blockIdx.y * 64;
  const int ty = tid >> 4, tx = tid & 15;
  float acc[4][4] = {};
  for (int kc = 0; kc < K; kc += 32) {
    __syncthreads();
#pragma unroll
    for (int rep = 0; rep < 8; ++rep) {
      const int l = tid + rep * 256;
      const int row = l >> 5, kk = l & 31;
      sA[row * 33 + kk] = A[(size_t)(r0 + row) * K + kc + kk];
      sB[row * 33 + kk] = Wt[(size_t)(n0 + row) * K + kc + kk];
    }
    __syncthreads();
#pragma unroll 8
    for (int kk = 0; kk < 32; ++kk) {
      const float a0 = sA[(ty * 4 + 0) * 33 + kk];
      const float a1 = sA[(ty * 4 + 1) * 33 + kk];
      const float a2 = sA[(ty * 4 + 2) * 33 + kk];
      const float a3 = sA[(ty * 4 + 3) * 33 + kk];
      const float b0 = sB[(tx * 4 + 0) * 33 + kk];
      const float b1 = sB[(tx * 4 + 1) * 33 + kk];
      const float b2 = sB[(tx * 4 + 2) * 33 + kk];
      const float b3 = sB[(tx * 4 + 3) * 33 + kk];
      acc[0][0] = fmaf(a0, b0, acc[0][0]); acc[0][1] = fmaf(a0, b1, acc[0][1]);
      acc[0][2] = fmaf(a0, b2, acc[0][2]); acc[0][3] = fmaf(a0, b3, acc[0][3]);
      acc[1][0] = fmaf(a1, b0, acc[1][0]); acc[1][1] = fmaf(a1, b1, acc[1][1]);
      acc[1][2] = fmaf(a1, b2, acc[1][2]); acc[1][3] = fmaf(a1, b3, acc[1][3]);
      acc[2][0] = fmaf(a2, b0, acc[2][0]); acc[2][1] = fmaf(a2, b1, acc[2][1]);
      acc[2][2] = fmaf(a2, b2, acc[2][2]); acc[2][3] = fmaf(a2, b3, acc[2][3]);
      acc[3][0] = fmaf(a3, b0, acc[3][0]); acc[3][1] = fmaf(a3, b1, acc[3][1]);
      acc[3][2] = fmaf(a3, b2, acc[3][2]); acc[3][3] = fmaf(a3, b3, acc[3][3]);
    }
  }
#pragma unroll
  for (int i = 0; i < 4; ++i)
#pragma unroll
    for (int j = 0; j < 4; ++j)
      out[(size_t)(r0 + ty * 4 + i) * N + n0 + tx * 4 + j] =
          acc[i][j] + bias[n0 + tx * 4 + j];
}

// ---------------------------------------------------------------------------
// GRU, both branches (grid 191). fp32 xy + bf16 xy_bf; logits (eval);
// t^T bf16 scatter (template).
// ---------------------------------------------------------------------------
__global__ __launch_bounds__(256) void gru_rec_kernel(
    float* __restrict__ xyE, const float* __restrict__ giE,
    const float* __restrict__ whhE, const float* __restrict__ bhhE,
    float* __restrict__ xyT, const float* __restrict__ giT,
    const float* __restrict__ whhT, const float* __restrict__ bhhT,
    u16* __restrict__ xybfE, u16* __restrict__ xybfT, u16* __restrict__ ttbf,
    const float* __restrict__ a_w, const float* __restrict__ a_b,
    float* __restrict__ logits) {
  const int bxid = blockIdx.x;
  const bool ev = bxid < 127;
  float* xy = ev ? xyE : xyT;
  u16* xybf = ev ? xybfE : xybfT;
  const float* gi = ev ? giE : giT;
  const float* whh = ev ? whhE : whhT;
  const float* bhh = ev ? bhhE : bhhT;
  const int T = ev ? 2032 : 1024;
  const int t0 = (ev ? bxid : bxid - 127) * 16;
  __shared__ float s_whh_t[64 * 192];
  __shared__ float s_h[16][64];
  __shared__ float s_aw[64];
  const int tid = threadIdx.x;
  const int lane = tid & 63, wave = tid >> 6;
  for (int i = tid; i < 192 * 64; i += 256) {
    const int j = i >> 6, d = i & 63;
    s_whh_t[d * 192 + j] = whh[i];
  }
  for (int i = tid; i < 16 * 64; i += 256) (&s_h[0][0])[i] = 0.f;
  if (tid < 64) s_aw[tid] = a_w[tid];
  const float ab = a_b[0];
  const float bhr = bhh[lane], bhz = bhh[64 + lane], bhn = bhh[128 + lane];
  __syncthreads();
  for (int b = 0; b < 4; ++b) {
    float gir[4], giz[4], gin[4];
#pragma unroll
    for (int sl = 0; sl < 4; ++sl) {
      int t = t0 + wave * 4 + sl; if (t > T - 1) t = T - 1;
      const float* girow = gi + ((size_t)b * T + t) * 192;
      gir[sl] = girow[lane]; giz[sl] = girow[64 + lane]; gin[sl] = girow[128 + lane];
    }
    float ahr[4] = {}, ahz[4] = {}, ahn[4] = {};
    for (int d = 0; d < 64; ++d) {
      const float wr_ = s_whh_t[d * 192 + lane];
      const float wz_ = s_whh_t[d * 192 + 64 + lane];
      const float wn_ = s_whh_t[d * 192 + 128 + lane];
#pragma unroll
      for (int sl = 0; sl < 4; ++sl) {
        const float hv = s_h[wave * 4 + sl][d];
        ahr[sl] = fmaf(wr_, hv, ahr[sl]);
        ahz[sl] = fmaf(wz_, hv, ahz[sl]);
        ahn[sl] = fmaf(wn_, hv, ahn[sl]);
      }
    }
    float hn[4];
#pragma unroll
    for (int sl = 0; sl < 4; ++sl) {
      const float r = 1.f / (1.f + __expf(-(gir[sl] + ahr[sl] + bhr)));
      const float z = 1.f / (1.f + __expf(-(giz[sl] + ahz[sl] + bhz)));
      const float n = tanhf(gin[sl] + r * (ahn[sl] + bhn));
      hn[sl] = (1.f - z) * n + z * s_h[wave * 4 + sl][lane];
    }
    __syncthreads();
#pragma unroll
    for (int sl = 0; sl < 4; ++sl) {
      const int t = t0 + wave * 4 + sl;
      s_h[wave * 4 + sl][lane] = hn[sl];
      if (t < T) {
        const size_t idx = ((size_t)b * T + t) * 64 + lane;
        xy[idx] = hn[sl];
        xybf[idx] = f2bf(hn[sl]);
        if (ev) {
          float v = hn[sl] * s_aw[lane];
#pragma unroll
          for (int off = 32; off > 0; off >>= 1) v += __shfl_down(v, off, 64);
          if (lane == 0) logits[b * 2032 + t] = v + ab;
        } else {
          ttbf[((size_t)b * 64 + lane) * 1024 + t] = f2bf(hn[sl]);
        }
      }
    }
    __syncthreads();
  }
}

// ---------------------------------------------------------------------------
// rowsum: rs[b,tau] = sum_eps exp(t[tau]·e[eps]). No P materialization.
// |s| <= 64 so exp never overflows. grid (16,16,4).
// ---------------------------------------------------------------------------
__global__ __launch_bounds__(256) void rowsum_kernel(
    const u16* __restrict__ tbf, const u16* __restrict__ ebf,
    float* __restrict__ rowsum) {
  __shared__ __align__(16) u16 sA[64 * 72];
  __shared__ __align__(16) u16 sB[128 * 72];
  const int tid = threadIdx.x;
  const int b = blockIdx.z;
  const int tau0 = blockIdx.x * 64;
  const int e0 = blockIdx.y * 128;
  const int lane = tid & 63, wave = tid >> 6;
  const int l31 = lane & 31, g8 = (lane >> 5) * 8;
  {
    const int row = tid >> 2, seg = (tid & 3) * 16;
    const u16* ap = &tbf[((size_t)b * 1024 + tau0 + row) * 64 + seg];
    u16* da = &sA[row * 72 + seg];
    *(u16x8*)da = *(const u16x8*)ap;
    *(u16x8*)(da + 8) = *(const u16x8*)(ap + 8);
  }
#pragma unroll
  for (int r = 0; r < 4; ++r) {
    const int q = tid + r * 256;
    const int row = q >> 3, seg = (q & 7) * 8;
    int eps = e0 + row; if (eps > 2031) eps = 2031;
    *(u16x8*)&sB[row * 72 + seg] =
        *(const u16x8*)&ebf[((size_t)b * 2032 + eps) * 64 + seg];
  }
  __syncthreads();
  const int mh = (wave & 1) * 32;
  const int nq = (wave >> 1) * 64;
  f32x16 acc0 = {}, acc1 = {};
#pragma unroll
  for (int ks = 0; ks < 4; ++ks) {
    bf16x8 a = *(const bf16x8*)&sA[(mh + l31) * 72 + ks * 16 + g8];
    bf16x8 b0 = *(const bf16x8*)&sB[(nq + l31) * 72 + ks * 16 + g8];
    bf16x8 b1 = *(const bf16x8*)&sB[(nq + 32 + l31) * 72 + ks * 16 + g8];
    acc0 = __builtin_amdgcn_mfma_f32_32x32x16_bf16(a, b0, acc0, 0, 0, 0);
    acc1 = __builtin_amdgcn_mfma_f32_32x32x16_bf16(a, b1, acc1, 0, 0, 0);
  }
  const int ep0 = e0 + nq + l31;
  const int ep1 = ep0 + 32;
#pragma unroll
  for (int r = 0; r < 16; ++r) {
    const int tau = tau0 + mh + (r & 3) + 8 * (r >> 2) + (g8 >> 1);
    float part = 0.f;
    if (ep0 < 2032) part += __expf(acc0[r]);
    if (ep1 < 2032) part += __expf(acc1[r]);
#pragma unroll
    for (int off = 16; off > 0; off >>= 1) part += __shfl_down(part, off, 32);
    if (l31 == 0) atomicAdd(&rowsum[b * 1024 + tau], part);
  }
}

// ---------------------------------------------------------------------------
// att softmax: attw[b,i] = softmax(logits[b,:])[i]. grid 4.
// ---------------------------------------------------------------------------
__global__ __launch_bounds__(256) void att_softmax_kernel(
    const float* __restrict__ logits, float* __restrict__ attw) {
  __shared__ float s_att[2032];
  __shared__ float sred[4];
  const int tid = threadIdx.x;
  const int lane = tid & 63, wave = tid >> 6;
  const int b = blockIdx.x;
  float m = -3.4e38f;
  for (int i = tid; i < 2032; i += 256) {
    const float v = logits[b * 2032 + i];
    s_att[i] = v;
    m = fmaxf(m, v);
  }
#pragma unroll
  for (int off = 32; off > 0; off >>= 1) m = fmaxf(m, __shfl_down(m, off, 64));
  if (lane == 0) sred[wave] = m;
  __syncthreads();
  m = fmaxf(fmaxf(sred[0], sred[1]), fmaxf(sred[2], sred[3]));
  __syncthreads();
  float ssum = 0.f;
  for (int i = tid; i < 2032; i += 256) {
    const float v = __expf(s_att[i] - m);
    s_att[i] = v;
    ssum += v;
  }
#pragma unroll
  for (int off = 32; off > 0; off >>= 1) ssum += __shfl_down(ssum, off, 64);
  if (lane == 0) sred[wave] = ssum;
  __syncthreads();
  const float inv = 1.f / (sred[0] + sred[1] + sred[2] + sred[3]);
  for (int i = tid; i < 2032; i += 256) attw[b * 2032 + i] = s_att[i] * inv;
}

// ---------------------------------------------------------------------------
// pv_red: per (b, 64-eps) block, sweep all tau in 64-chunks: recompute
// QK^T (MFMA) + exp, normalize by preloaded 1/rs, LDS-transpose, MFMA-
// accumulate PV in registers; epilogue folds |PV-e|*att into red (atomic).
// PV never touches memory. grid (32, 4). LDS ~38KB.
// ---------------------------------------------------------------------------
__global__ __launch_bounds__(256) void pv_red_kernel(
    const u16* __restrict__ tbf, const u16* __restrict__ ebf,
    const u16* __restrict__ ttbf, const float* __restrict__ rowsum,
    const float* __restrict__ attw, const float* __restrict__ emat,
    float* __restrict__ red) {
  __shared__ __align__(16) u16 sE[64 * 72];   // e rows for this eps block
  __shared__ __align__(16) u16 sT[64 * 72];   // t chunk (tau rows)
  __shared__ __align__(16) u16 sTT[64 * 72];  // tt chunk ([d][tau])
  __shared__ __align__(16) u16 sPT[64 * 72];  // normalized P^T ([eps][tau])
  __shared__ float s_rs[64];                  // 1/rowsum for chunk
  __shared__ float s_att[64];                 // att weights for eps block
  __shared__ float s_part[4][32];
  const int tid = threadIdx.x;
  const int b = blockIdx.y;
  const int e0 = blockIdx.x * 64;
  const int lane = tid & 63, wave = tid >> 6;
  const int l31 = lane & 31, g8 = (lane >> 5) * 8;
  const int mh = (wave & 1) * 32;   // QK: tau half | PV: eps half
  const int nh = (wave >> 1) * 32;  // QK: eps half | PV: d half
  {
    const int row = tid >> 2, seg = (tid & 3) * 16;
    int eps = e0 + row; if (eps > 2031) eps = 2031;
    const u16* ap = &ebf[((size_t)b * 2032 + eps) * 64 + seg];
    u16* da = &sE[row * 72 + seg];
    *(u16x8*)da = *(const u16x8*)ap;
    *(u16x8*)(da + 8) = *(const u16x8*)(ap + 8);
  }
  if (tid < 64) {
    const int e = e0 + tid;
    s_att[tid] = (e < 2032) ? attw[b * 2032 + e] : 0.f;
  }
  f32x16 accPV = {};
  for (int ch = 0; ch < 16; ++ch) {
    const int tc = ch * 64;
    __syncthreads();  // prior MFMA reads done (and sE/s_att ready on ch==0)
    {
      const int row = tid >> 2, seg = (tid & 3) * 16;
      const u16* ap = &tbf[((size_t)b * 1024 + tc + row) * 64 + seg];
      u16* da = &sT[row * 72 + seg];
      *(u16x8*)da = *(const u16x8*)ap;
      *(u16x8*)(da + 8) = *(const u16x8*)(ap + 8);
    }
#pragma unroll
    for (int k = 0; k < 2; ++k) {
      const int q = tid + k * 256;
      const int row = q >> 3, seg = (q & 7) * 8;
      *(u16x8*)&sTT[row * 72 + seg] =
          *(const u16x8*)&ttbf[((size_t)b * 64 + row) * 1024 + tc + seg];
    }
    if (tid < 64) s_rs[tid] = 1.0f / rowsum[b * 1024 + tc + tid];
    __syncthreads();  // sT/sTT/s_rs ready
    // QK: s[tau(mh), eps(nh)], k=64
    f32x16 acc = {};
#pragma unroll
    for (int ks = 0; ks < 4; ++ks) {
      bf16x8 a = *(const bf16x8*)&sT[(mh + l31) * 72 + ks * 16 + g8];
      bf16x8 bb = *(const bf16x8*)&sE[(nh + l31) * 72 + ks * 16 + g8];
      acc = __builtin_amdgcn_mfma_f32_32x32x16_bf16(a, bb, acc, 0, 0, 0);
    }
    // normalize + transposed store sPT[eps][tau]
#pragma unroll
    for (int r = 0; r < 16; ++r) {
      const int tl = mh + (r & 3) + 8 * (r >> 2) + (g8 >> 1);
      const int el = nh + l31;
      sPT[el * 72 + tl] = f2bf(__expf(acc[r]) * s_rs[tl]);
    }
    __syncthreads();  // sPT ready
    // PV: accPV[eps(mh), d(nh)] += sPT x sTT, k=tau
#pragma unroll
    for (int ks = 0; ks < 4; ++ks) {
      bf16x8 a = *(const bf16x8*)&sPT[(mh + l31) * 72 + ks * 16 + g8];
      bf16x8 bb = *(const bf16x8*)&sTT[(nh + l31) * 72 + ks * 16 + g8];
      accPV = __builtin_amdgcn_mfma_f32_32x32x16_bf16(a, bb, accPV, 0, 0, 0);
    }
  }
  // epilogue: red[b,d] += sum_eps |PV - e| * att  (PV never stored)
  float local = 0.f;
#pragma unroll
  for (int r = 0; r < 16; ++r) {
    const int el = mh + (r & 3) + 8 * (r >> 2) + (g8 >> 1);
    const int eps = e0 + el;
    if (eps < 2032) {
      const size_t idx = ((size_t)b * 2032 + eps) * 64 + nh + l31;
      local = fmaf(fabsf(accPV[r] - emat[idx]), s_att[el], local);
    }
  }
  local += __shfl_xor(local, 32, 64);  // merge g8 groups (same d)
  if (lane < 32) s_part[wave][lane] = local;
  __syncthreads();
  if (tid < 64) {
    const int d = tid;
    const float v = (d < 32) ? (s_part[0][d] + s_part[1][d])
                             : (s_part[2][d - 32] + s_part[3][d - 32]);
    atomicAdd(&red[b * 64 + d], v);
  }
}

// ---------------------------------------------------------------------------
// mlp: h = relu(red@h_w^T + h_b); out = softmax(h@c_w^T + c_b). grid 4.
// ---------------------------------------------------------------------------
__global__ __launch_bounds__(128) void mlp_kernel(
    const float* __restrict__ red, const float* __restrict__ h_w,
    const float* __restrict__ h_b, const float* __restrict__ c_w,
    const float* __restrict__ c_b, float* __restrict__ out) {
  __shared__ float s_red[64];
  __shared__ float s_hv[128];
  const int tid = threadIdx.x;
  const int b = blockIdx.x;
  if (tid < 64) s_red[tid] = red[b * 64 + tid];
  __syncthreads();
  {
    float acc = h_b[tid];
    const float* hw = h_w + tid * 64;
    for (int d = 0; d < 64; ++d) acc = fmaf(s_red[d], hw[d], acc);
    s_hv[tid] = fmaxf(acc, 0.f);
  }
  __syncthreads();
  if (tid == 0) {
    float l0 = c_b[0], l1 = c_b[1];
    for (int j = 0; j < 128; ++j) {
      l0 = fmaf(s_hv[j], c_w[j], l0);
      l1 = fmaf(s_hv[j], c_w[128 + j], l1);
    }
    const float mm = fmaxf(l0, l1);
    const float e0 = __expf(l0 - mm), e1 = __expf(l1 - mm);
    const float invs = 1.f / (e0 + e1);
    out[b * 2 + 0] = e0 * invs;
    out[b * 2 + 1] = e1 * invs;
  }
}

// ===========================================================================
extern "C" void kernel_launch(void* const* d_in, const int* in_sizes, int n_in,
                              void* d_out, int out_size, void* d_ws, size_t ws_size,
                              hipStream_t stream) {
  const float* evaluation = (const float*)d_in[0];
  const float* templ      = (const float*)d_in[1];
  const float* e_w1 = (const float*)d_in[2];
  const float* e_b1 = (const float*)d_in[3];
  const float* e_w2 = (const float*)d_in[4];
  const float* e_b2 = (const float*)d_in[5];
  const float* e_w3 = (const float*)d_in[6];
  const float* e_b3 = (const float*)d_in[7];
  const float* el_w = (const float*)d_in[8];
  const float* el_b = (const float*)d_in[9];
  const float* eg_wih = (const float*)d_in[10];
  const float* eg_whh = (const float*)d_in[11];
  const float* eg_bih = (const float*)d_in[12];
  const float* eg_bhh = (const float*)d_in[13];
  const float* t_w1 = (const float*)d_in[14];
  const float* t_b1 = (const float*)d_in[15];
  const float* t_w2 = (const float*)d_in[16];
  const float* t_b2 = (const float*)d_in[17];
  const float* t_w3 = (const float*)d_in[18];
  const float* t_b3 = (const float*)d_in[19];
  const float* tl_w = (const float*)d_in[20];
  const float* tl_b = (const float*)d_in[21];
  const float* tg_wih = (const float*)d_in[22];
  const float* tg_whh = (const float*)d_in[23];
  const float* tg_bih = (const float*)d_in[24];
  const float* tg_bhh = (const float*)d_in[25];
  const float* a_w = (const float*)d_in[26];
  const float* a_b = (const float*)d_in[27];
  const float* h_w = (const float*)d_in[28];
  const float* h_b = (const float*)d_in[29];
  const float* c_w = (const float*)d_in[30];
  const float* c_b = (const float*)d_in[31];

  float* ws = (float*)d_ws;
  float* beff_e  = ws + OFF_BEFF_E;
  float* beff_t  = ws + OFF_BEFF_T;
  float* bias2_e = ws + OFF_BIAS2_E;
  float* bias2_t = ws + OFF_BIAS2_T;
  u16*   wkx_e   = (u16*)(ws + OFF_WKX_E);
  u16*   wkx_t   = (u16*)(ws + OFF_WKX_T);
  float* w12p_e  = ws + OFF_W12P_E;
  float* w12p_t  = ws + OFF_W12P_T;
  float* b12_e   = ws + OFF_B12_E;
  float* b12_t   = ws + OFF_B12_T;
  u16*   lwt1_e  = (u16*)(ws + OFF_LWT1_E);
  u16*   lwt1_t  = (u16*)(ws + OFF_LWT1_T);
  float* attbuf  = ws + OFF_ATT;
  u16*   xybf_e  = (u16*)(ws + OFF_XYBF_E);
  u16*   xybf_t  = (u16*)(ws + OFF_XYBF_T);
  u16*   ttbf    = (u16*)(ws + OFF_TTBF);
  float* lin_e   = ws + OFF_LIN_E;
  float* lin_t   = ws + OFF_LIN_T;
  float* redbuf  = ws + OFF_RED;
  float* rsum    = ws + OFF_RSUM;
  float* attw    = ws + OFF_ATTW;
  float* gi_e    = ws + OFF_GI_E;
  float* gi_t    = ws + OFF_GI_T;

  // prep (zeroes lin/red/rowsum + compose12 + gi_bias + lw->lwT1), weff
  prep_kernel<<<530, 320, 0, stream>>>(
      e_w1, e_b1, e_w2, e_b2, t_w1, t_b1, t_w2, t_b2, w12p_e, w12p_t, b12_e, b12_t,
      eg_wih, eg_bih, el_b, bias2_e, tg_wih, tg_bih, tl_b, bias2_t,
      el_w, tl_w, lwt1_e, lwt1_t, (float4*)lin_e);
  compose_weff_kernel<<<dim3(64, 2), 256, 0, stream>>>(
      e_w3, e_b3, t_w3, t_b3, w12p_e, w12p_t, b12_e, b12_t, wkx_e, wkx_t, beff_e, beff_t);

  // fused conv+pool+linear (atomic into lin), then GRU chain
  conv_pool_lin_kernel<<<dim3(34, 10, 8), 256, 0, stream>>>(
      evaluation, wkx_e, beff_e, lwt1_e, lin_e,
      templ, wkx_t, beff_t, lwt1_t, lin_t);
  gemm_gi_kernel<<<dim3(191, 3), 256, 0, stream>>>(
      lin_e, eg_wih, bias2_e, gi_e, lin_t, tg_wih, bias2_t, gi_t);
  gru_rec_kernel<<<191, 256, 0, stream>>>(
      lin_e, gi_e, eg_whh, eg_bhh, lin_t, gi_t, tg_whh, tg_bhh,
      xybf_e, xybf_t, ttbf, a_w, a_b, attbuf);

  // cross attention, P-free: rowsums -> att weights -> fused pv+red
  rowsum_kernel<<<dim3(16, 16, 4), 256, 0, stream>>>(xybf_t, xybf_e, rsum);
  att_softmax_kernel<<<4, 256, 0, stream>>>(attbuf, attw);
  pv_red_kernel<<<dim3(32, 4), 256, 0, stream>>>(
      xybf_t, xybf_e, ttbf, rsum, attw, lin_e, redbuf);

  // head MLP
  mlp_kernel<<<4, 128, 0, stream>>>(redbuf, h_w, h_b, c_w, c_b, (float*)d_out);
}